// Round 7
// baseline (699.232 us; speedup 1.0000x reference)
//
#include <hip/hip_runtime.h>
#include <hip/hip_bf16.h>
#include <math.h>

using bf16 = __hip_bfloat16;

__device__ __forceinline__ float b2f(bf16 v) { return __bfloat162float(v); }
// mode: 1 = inputs bf16, 0 = inputs f32
__device__ __forceinline__ float ldv(const void* p, size_t i, int m) {
  return m ? b2f(((const bf16*)p)[i]) : ((const float*)p)[i];
}

// pack two f32 -> (bf16 lo | bf16 hi<<16), RNE
__device__ __forceinline__ unsigned pk2(float a, float b) {
  union { bf16 h; unsigned short u; } ca, cb;
  ca.h = __float2bfloat16(a); cb.h = __float2bfloat16(b);
  return (unsigned)ca.u | ((unsigned)cb.u << 16);
}
__device__ __forceinline__ float lo2f(unsigned u) { return __uint_as_float(u << 16); }
__device__ __forceinline__ float hi2f(unsigned u) { return __uint_as_float(u & 0xFFFF0000u); }

struct D2 { double s, s2; };

// ---- block reductions (blockDim == 256), non-atomic partial writes ----
__device__ __forceinline__ void block_stats1(float v, D2* slot) {
  float v2 = v * v;
#pragma unroll
  for (int o = 32; o; o >>= 1) { v += __shfl_down(v, o, 64); v2 += __shfl_down(v2, o, 64); }
  __shared__ float a1[4], a2[4];
  int lane = threadIdx.x & 63, w = threadIdx.x >> 6;
  if (lane == 0) { a1[w] = v; a2[w] = v2; }
  __syncthreads();
  if (threadIdx.x == 0) {
    slot->s  = (double)a1[0] + a1[1] + a1[2] + a1[3];
    slot->s2 = (double)a2[0] + a2[1] + a2[2] + a2[3];
  }
}

// 4 doubles at once (single barrier, no cross-call race)
__device__ __forceinline__ void block_stats1d4(const double* v, const double* vq, D2* base, int NB, int bx) {
  __shared__ double q1[16], q2[16];
  int lane = threadIdx.x & 63, w = threadIdx.x >> 6;
#pragma unroll
  for (int k = 0; k < 4; k++) {
    double s = v[k], s2 = vq[k];
#pragma unroll
    for (int o = 32; o; o >>= 1) { s += __shfl_down(s, o, 64); s2 += __shfl_down(s2, o, 64); }
    if (lane == 0) { q1[k * 4 + w] = s; q2[k * 4 + w] = s2; }
  }
  __syncthreads();
  if (threadIdx.x < 4) {
    int k = threadIdx.x;
    base[k * NB + bx].s  = q1[k * 4] + q1[k * 4 + 1] + q1[k * 4 + 2] + q1[k * 4 + 3];
    base[k * NB + bx].s2 = q2[k * 4] + q2[k * 4 + 1] + q2[k * 4 + 2] + q2[k * 4 + 3];
  }
}

__device__ __forceinline__ void block_sum1(float v, double* slot) {
#pragma unroll
  for (int o = 32; o; o >>= 1) v += __shfl_down(v, o, 64);
  __shared__ float a1[4];
  int lane = threadIdx.x & 63, w = threadIdx.x >> 6;
  if (lane == 0) a1[w] = v;
  __syncthreads();
  if (threadIdx.x == 0) *slot = (double)a1[0] + a1[1] + a1[2] + a1[3];
}

// 16-channel block stats -> part[co*NB + bx]
__device__ __forceinline__ void block_stats16(const float* vs, const float* vq, D2* base, int NB, int bx) {
  __shared__ float s1[64], s2[64];
  int lane = threadIdx.x & 63, w = threadIdx.x >> 6;
#pragma unroll
  for (int co = 0; co < 16; co++) {
    float v = vs[co], v2 = vq[co];
#pragma unroll
    for (int o = 32; o; o >>= 1) { v += __shfl_down(v, o, 64); v2 += __shfl_down(v2, o, 64); }
    if (lane == 0) { s1[co * 4 + w] = v; s2[co * 4 + w] = v2; }
  }
  __syncthreads();
  if (threadIdx.x < 16) {
    int co = threadIdx.x;
    base[co * NB + bx].s  = (double)s1[co * 4] + s1[co * 4 + 1] + s1[co * 4 + 2] + s1[co * 4 + 3];
    base[co * NB + bx].s2 = (double)s2[co * 4] + s2[co * 4 + 1] + s2[co * 4 + 2] + s2[co * 4 + 3];
  }
}

// PF float layout: W1 0(256) B1 256(16)
//   W2N 272(4096,[cig*1024+tap*64+c4*16+co])  <- conv2 pass-major layout
//   B2 4368(16)
//   WD1 4384(1024, legacy) BD1 5408(16) WD2 5424(4096, legacy)
//   BD2 9520(16) WD3 9536(256, legacy) BD3 9792(1) G/BE 9856+l*32 (gamma 16, beta 16)
//   WD3T 10016(256,[tap*16+ci])   <- tap-major copy for deconv3
//   WD2T 10272(4096,[ci*256+tap*16+co]) <- co-contiguous per (ci,tap) for deconv2
//   WD1T 14368(1024,[ci*256+tap*16+co]) <- co-contiguous per (ci,tap) for deconv1
// PD double layout: W3 0(1024,[co*256+ci*16+tap]) B3 1024(4) WPRE 1028(8) BPRE 1036(2)
//   CB 1040(512) WPOST 1552(8) BPOST 1560(4)
__global__ void prep_k(const unsigned* __restrict__ xw, int* __restrict__ MODE,
                       const void* w1, const void* b1, const void* w2, const void* b2,
                       const void* w3, const void* b3, const void* wpre, const void* bpre,
                       const void* cbk, const void* wpost, const void* bpost,
                       const void* wd1, const void* bd1, const void* wd2, const void* bd2,
                       const void* wd3, const void* bd3,
                       const void* g1, const void* be1, const void* g2, const void* be2,
                       const void* g3, const void* be3, const void* g4, const void* be4,
                       const void* g5, const void* be5,
                       float* __restrict__ PF, double* __restrict__ PD) {
  int t = threadIdx.x;
  // ---- dtype detect (merged init) ----
  __shared__ int smode;
  {
    unsigned lo = xw[t] & 0xFFFFu;
    int inr = (lo >= 0x3000u && lo < 0x4000u) ? 1 : 0;
    unsigned long long b = __ballot(inr);
    __shared__ int cnt[4];
    if ((t & 63) == 0) cnt[t >> 6] = __popcll(b);
    __syncthreads();
    if (t == 0) { smode = (cnt[0] + cnt[1] + cnt[2] + cnt[3] >= 128) ? 1 : 0; *MODE = smode; }
    __syncthreads();
  }
  int m = smode;
  for (int i = t; i < 256; i += 256) PF[i] = ldv(w1, i, m);
  if (t < 16) PF[256 + t] = ldv(b1, t, m);
  for (int i = t; i < 4096; i += 256) {   // w2 (16,16,4,4) -> [cig*1024+tap*64+c4*16+co]
    int cig = i >> 10, tap = (i >> 6) & 15, c4 = (i >> 4) & 3, co = i & 15;
    PF[272 + i] = ldv(w2, co * 256 + (cig * 4 + c4) * 16 + tap, m);
  }
  if (t < 16) PF[4368 + t] = ldv(b2, t, m);
  for (int i = t; i < 1024; i += 256) {   // wd1 (4,16,4,4) -> [co*64+ci*16+tap] (legacy)
    int co = i >> 6, ci = (i >> 4) & 3, tap = i & 15;
    PF[4384 + i] = ldv(wd1, ci * 256 + co * 16 + tap, m);
  }
  for (int i = t; i < 1024; i += 256) {   // wd1 -> [ci*256+tap*16+co]
    int ci = i >> 8, tap = (i >> 4) & 15, co = i & 15;
    PF[14368 + i] = ldv(wd1, ci * 256 + co * 16 + tap, m);
  }
  if (t < 16) PF[5408 + t] = ldv(bd1, t, m);
  for (int i = t; i < 4096; i += 256) {   // wd2 legacy
    int co = i >> 8, ci = (i >> 4) & 15, tap = i & 15;
    PF[5424 + i] = ldv(wd2, ci * 256 + co * 16 + tap, m);
  }
  for (int i = t; i < 4096; i += 256) {   // wd2 -> [ci*256+tap*16+co]
    int ci = i >> 8, tap = (i >> 4) & 15, co = i & 15;
    PF[10272 + i] = ldv(wd2, ci * 256 + co * 16 + tap, m);
  }
  if (t < 16) PF[9520 + t] = ldv(bd2, t, m);
  for (int i = t; i < 256; i += 256) PF[9536 + i] = ldv(wd3, i, m);
  {   // tap-major wd3: WT[tap*16 + ci] = wd3[ci*16 + tap]
    int tap = t >> 4, ci = t & 15;
    PF[10016 + t] = ldv(wd3, ci * 16 + tap, m);
  }
  if (t == 0) PF[9792] = ldv(bd3, 0, m);
  if (t < 16) {
    PF[9856 + t] = ldv(g1, t, m);  PF[9872 + t] = ldv(be1, t, m);
    PF[9888 + t] = ldv(g2, t, m);  PF[9904 + t] = ldv(be2, t, m);
    PF[9952 + t] = ldv(g4, t, m);  PF[9968 + t] = ldv(be4, t, m);
    PF[9984 + t] = ldv(g5, t, m);  PF[10000 + t] = ldv(be5, t, m);
  }
  if (t < 4) { PF[9920 + t] = ldv(g3, t, m); PF[9936 + t] = ldv(be3, t, m); }
  for (int i = t; i < 1024; i += 256) PD[i] = ldv(w3, i, m);
  if (t < 4) PD[1024 + t] = ldv(b3, t, m);
  if (t < 8) PD[1028 + t] = ldv(wpre, t, m);
  if (t < 2) PD[1036 + t] = ldv(bpre, t, m);
  for (int i = t; i < 512; i += 256) PD[1040 + i] = ldv(cbk, i, m);
  if (t < 8) PD[1552 + t] = ldv(wpost, t, m);
  if (t < 4) PD[1560 + t] = ldv(bpost, t, m);
}

// ---- BN reduce: partials -> scale/shift (f64 + f32) ----
__global__ __launch_bounds__(256) void bn_reduce_k(const D2* __restrict__ part, int NB,
                                                   double* __restrict__ stD, float* __restrict__ stF,
                                                   const float* __restrict__ gb, double invN) {
  int c = blockIdx.x;
  double s = 0, s2 = 0;
  for (int i = threadIdx.x; i < NB; i += 256) { D2 p = part[c * NB + i]; s += p.s; s2 += p.s2; }
#pragma unroll
  for (int o = 32; o; o >>= 1) { s += __shfl_down(s, o, 64); s2 += __shfl_down(s2, o, 64); }
  __shared__ double l1[4], l2[4];
  int lane = threadIdx.x & 63, w = threadIdx.x >> 6;
  if (lane == 0) { l1[w] = s; l2[w] = s2; }
  __syncthreads();
  if (threadIdx.x == 0) {
    double S = l1[0] + l1[1] + l1[2] + l1[3], Q = l2[0] + l2[1] + l2[2] + l2[3];
    double mu = S * invN, var = Q * invN - mu * mu;
    if (var < 0) var = 0;
    double sc = (double)gb[c] / sqrt(var + 1e-5);
    double sh = (double)gb[16 + c] - mu * sc;
    stD[c] = sc; stD[16 + c] = sh;
    stF[c] = (float)sc; stF[16 + c] = (float)sh;
  }
}

// ---- conv1 tiled: 64x4 tile, all 16 co per block, x staged once in LDS ----
// Output H1 is channel-group planar: plane g (g=co>>2) is [b][y][x][4],
// plane stride 8388608 floats (32 MB). Pixel index pix=(b*65536+oy*256+ox).
__global__ __launch_bounds__(256) void conv1_t(const void* __restrict__ x, const float* __restrict__ PF,
                                               float* __restrict__ y, D2* __restrict__ part,
                                               const int* modep) {
  const int m = *modep;
  __shared__ float sx[10 * 130];
  int t = threadIdx.x;
  int bx = blockIdx.x;
  int b = bx >> 8, r = bx & 255, tY = r >> 2, tX = r & 3;   // 64 tY x 4 tX tiles of 64x4
  int iy0 = 8 * tY - 1, ix0 = 128 * tX - 1;
  size_t xb = (size_t)b * 262144;
  for (int i = t; i < 1300; i += 256) {
    int ry = i / 130, rx = i - ry * 130;
    int gy = iy0 + ry, gx = ix0 + rx;
    float v = 0.f;
    if ((unsigned)gy < 512u && (unsigned)gx < 512u) v = ldv(x, xb + (size_t)gy * 512 + gx, m);
    sx[i] = v;
  }
  __syncthreads();
  int tyy = t >> 6, txx = t & 63;
  int oy = tY * 4 + tyy, ox = tX * 64 + txx;
  float acc[16];
#pragma unroll
  for (int co = 0; co < 16; co++) acc[co] = PF[256 + co];
  int ly = 2 * tyy, lx = 2 * txx;
#pragma unroll
  for (int ky = 0; ky < 4; ky++) {
#pragma unroll
    for (int kx = 0; kx < 4; kx++) {
      float v = sx[(ly + ky) * 130 + lx + kx];
#pragma unroll
      for (int co = 0; co < 16; co++) acc[co] = fmaf(v, PF[co * 16 + ky * 4 + kx], acc[co]);
    }
  }
  size_t pix = (size_t)b * 65536 + (size_t)(oy * 256 + ox);
  *(float4*)(y + 0 * 8388608 + pix * 4) = make_float4(acc[0],  acc[1],  acc[2],  acc[3]);
  *(float4*)(y + 1 * 8388608 + pix * 4) = make_float4(acc[4],  acc[5],  acc[6],  acc[7]);
  *(float4*)(y + 2 * 8388608 + pix * 4) = make_float4(acc[8],  acc[9],  acc[10], acc[11]);
  *(float4*)(y + 3 * 8388608 + pix * 4) = make_float4(acc[12], acc[13], acc[14], acc[15]);
  float vq_[16];
#pragma unroll
  for (int co = 0; co < 16; co++) vq_[co] = acc[co] * acc[co];
  block_stats16(acc, vq_, part, 8192, bx);
}

// ---- conv2: g-planar input, 4 passes of 4 ci each, async-stage prefetch.
// ---- OOB halo must stage EXACT ZERO (conv zero-pad of the post-BN-relu
// ---- input) -- affine is applied only to in-bounds values (R6 bugfix).
__device__ __forceinline__ float4 aff_relu4(float4 v, float4 sc, float4 sh) {
  v.x = fmaxf(fmaf(v.x, sc.x, sh.x), 0.f);
  v.y = fmaxf(fmaf(v.y, sc.y, sh.y), 0.f);
  v.z = fmaxf(fmaf(v.z, sc.z, sh.z), 0.f);
  v.w = fmaxf(fmaf(v.w, sc.w, sh.w), 0.f);
  return v;
}

__global__ __launch_bounds__(256, 6) void conv2_t(const float* __restrict__ h1, const float* __restrict__ PF,
                                                  const float* __restrict__ aff, float* __restrict__ h2,
                                                  D2* __restrict__ part) {
  __shared__ float su[4896];   // [q][plane][34][18]
  int t = threadIdx.x, ty = t >> 4, tx = t & 15;
  int bx = blockIdx.x, bb = bx >> 6, r = bx & 63, tY = r >> 3, tX = r & 7;
  int oy = tY * 16 + ty, ox = tX * 16 + tx;
  int iy0 = 32 * tY - 1, ix0 = 32 * tX - 1;
  const float* W2 = PF + 272;              // [cig*1024 + tap*64 + c4*16 + co]
  const float4* A4 = (const float4*)aff;
  // precompute staging geometry (same for all g)
  int goff[5], soff[5];
#pragma unroll
  for (int k = 0; k < 5; k++) {
    int i = t + k * 256;
    goff[k] = -1; soff[k] = -1;
    if (i < 1156) {
      int riy = i / 34, rix = i - riy * 34;
      int gy = iy0 + riy, gx = ix0 + rix;
      soff[k] = (rix & 1) * 2448 + riy * 18 + (rix >> 1);
      if ((unsigned)gy < 256u && (unsigned)gx < 256u) goff[k] = (gy * 256 + gx) * 4;
    }
  }
  const float* pb = h1 + (size_t)bb * 262144;
  float4 rv[5];
#pragma unroll
  for (int k = 0; k < 5; k++) {
    float4 v = make_float4(0.f, 0.f, 0.f, 0.f);
    if (goff[k] >= 0) v = *(const float4*)(pb + goff[k]);
    rv[k] = v;
  }
  float acc[16];
#pragma unroll
  for (int co = 0; co < 16; co++) acc[co] = PF[4368 + co];
#pragma unroll
  for (int g = 0; g < 4; g++) {
    float4 SC = A4[g], SH = A4[4 + g];
    __syncthreads();
#pragma unroll
    for (int k = 0; k < 5; k++) {
      if (soff[k] >= 0) {
        float4 v = make_float4(0.f, 0.f, 0.f, 0.f);
        if (goff[k] >= 0) v = aff_relu4(rv[k], SC, SH);   // affine ONLY in-bounds; pad stays 0
        int s = soff[k];
        su[s] = v.x; su[612 + s] = v.y; su[1224 + s] = v.z; su[1836 + s] = v.w;
      }
    }
    __syncthreads();
    if (g < 3) {
      const float* pg = pb + (size_t)(g + 1) * 8388608;
#pragma unroll
      for (int k = 0; k < 5; k++) {
        float4 v = make_float4(0.f, 0.f, 0.f, 0.f);
        if (goff[k] >= 0) v = *(const float4*)(pg + goff[k]);
        rv[k] = v;
      }
    }
    const float* wg = W2 + g * 1024;
    int base = 2 * ty * 18 + tx;
#pragma unroll
    for (int ky = 0; ky < 4; ky++) {
#pragma unroll
      for (int kx = 0; kx < 4; kx++) {
        int s = (kx & 1) * 2448 + ky * 18 + (kx >> 1) + base;
        float v0 = su[s], v1 = su[612 + s], v2 = su[1224 + s], v3 = su[1836 + s];
        const float* wt = wg + (ky * 4 + kx) * 64;
#pragma unroll
        for (int co = 0; co < 16; co++) {
          float s0 = fmaf(v0, wt[co], acc[co]);
          float s1 = fmaf(v1, wt[16 + co], s0);
          float s2 = fmaf(v2, wt[32 + co], s1);
          acc[co] = fmaf(v3, wt[48 + co], s2);
        }
      }
    }
  }
  float vq_[16];
#pragma unroll
  for (int co = 0; co < 16; co++) {
    h2[((size_t)(bb * 16 + co) * 128 + oy) * 128 + ox] = acc[co];
    vq_[co] = acc[co] * acc[co];
  }
  block_stats16(acc, vq_, part, 2048, bx);
}

// ---- conv3: all 4 co per thread; f32 h2 (affine2+relu) -> f64 raw (32,4,64,64) ----
__global__ __launch_bounds__(256) void conv3_k(const float* __restrict__ h2, const double* __restrict__ PD,
                                               const float* __restrict__ aff, double* __restrict__ c3,
                                               D2* __restrict__ part) {
  int idx = blockIdx.x * 256 + threadIdx.x;   // 131072
  int b = idx >> 12, rem = idx & 4095, oy = rem >> 6, ox = rem & 63;
  double a0 = PD[1024], a1 = PD[1025], a2 = PD[1026], a3 = PD[1027];
  int iy0 = 2 * oy - 1, ix0 = 2 * ox - 1;
  for (int ci = 0; ci < 16; ci++) {
    const float* ib = h2 + (size_t)(b * 16 + ci) * 16384;
    float sc = aff[ci], sh = aff[16 + ci];
    const double* wr = PD + ci * 16;   // + co*256 per output
#pragma unroll
    for (int ky = 0; ky < 4; ky++) {
      int iy = iy0 + ky;
      if ((unsigned)iy < 128u) {
        const float* row = ib + iy * 128;
#pragma unroll
        for (int kx = 0; kx < 4; kx++) {
          int ix = ix0 + kx;
          if ((unsigned)ix < 128u) {
            double v = (double)fmaxf(fmaf(row[ix], sc, sh), 0.f);
            int tp = ky * 4 + kx;
            a0 = fma(v, wr[tp], a0);
            a1 = fma(v, wr[256 + tp], a1);
            a2 = fma(v, wr[512 + tp], a2);
            a3 = fma(v, wr[768 + tp], a3);
          }
        }
      }
    }
  }
  size_t cb = (size_t)b * 16384 + rem;
  c3[cb] = a0; c3[cb + 4096] = a1; c3[cb + 8192] = a2; c3[cb + 12288] = a3;
  double vs[4] = {a0, a1, a2, a3};
  double vq[4] = {a0 * a0, a1 * a1, a2 * a2, a3 * a3};
  block_stats1d4(vs, vq, part, 512, blockIdx.x);
}

// ---- VQ: f64 BN3 affine+relu -> wpre -> argmin -> wpost -> d0 (f32) ----
__global__ __launch_bounds__(256) void vq_k(const double* __restrict__ c3, const double* __restrict__ PD,
                                            const double* __restrict__ stD2, float* __restrict__ d0,
                                            double* __restrict__ vp) {
  __shared__ double cb[512];
  for (int i = threadIdx.x; i < 512; i += 256) cb[i] = PD[1040 + i];
  __syncthreads();
  int pix = blockIdx.x * 256 + threadIdx.x;
  int b = pix >> 12, rem = pix & 4095;
  const double* hb = c3 + (size_t)b * 16384 + rem;
  double q0 = PD[1036], q1 = PD[1037];
#pragma unroll
  for (int ci = 0; ci < 4; ci++) {
    double v = fma(hb[ci * 4096], stD2[ci], stD2[16 + ci]);
    if (v < 0) v = 0;
    q0 = fma(v, PD[1028 + ci], q0);
    q1 = fma(v, PD[1032 + ci], q1);
  }
  int best = 0;
  double bd = 1e300;
  for (int k = 0; k < 256; k++) {
    double dx = q0 - cb[2 * k], dy = q1 - cb[2 * k + 1];
    double d = dx * dx + dy * dy;
    if (d < bd) { bd = d; best = k; }   // strict < == first-index argmin
  }
  double c0 = cb[2 * best], c1 = cb[2 * best + 1];
  double e0 = q0 - c0, e1 = q1 - c1;
  float* ob = d0 + (size_t)b * 16384 + rem;
#pragma unroll
  for (int c = 0; c < 4; c++)
    ob[c * 4096] = (float)(PD[1560 + c] + PD[1552 + 2 * c] * c0 + PD[1552 + 2 * c + 1] * c1);
  double v = e0 * e0 + e1 * e1;
#pragma unroll
  for (int o = 32; o; o >>= 1) v += __shfl_down(v, o, 64);
  __shared__ double l1[4];
  int lane = threadIdx.x & 63, w = threadIdx.x >> 6;
  if (lane == 0) l1[w] = v;
  __syncthreads();
  if (threadIdx.x == 0) vp[blockIdx.x] = l1[0] + l1[1] + l1[2] + l1[3];
}

// ---- deconv1: parity-phase grid (512, phase). d1 g-planar f32. ----
__global__ __launch_bounds__(256) void deconv1_k(const float* __restrict__ d0, const float* __restrict__ PF,
                                                 float* __restrict__ d1, D2* __restrict__ part) {
  int phase = blockIdx.y, a = phase >> 1, bc = phase & 1;
  int idx = blockIdx.x * 256 + threadIdx.x;   // 131072 quads
  int b = idx >> 12, rem = idx & 4095, qy = rem >> 6, qx = rem & 63;
  const float* WT = PF + 14368;   // [ci*256 + tap*16 + co]
  float acc[16];
#pragma unroll
  for (int co = 0; co < 16; co++) acc[co] = PF[5408 + co];
  const float* hb = d0 + (size_t)b * 16384;
#pragma unroll
  for (int t2y = 0; t2y < 2; t2y++) {
    int iy = qy + a - t2y;
    if ((unsigned)iy < 64u) {
      int kyo = (1 - a + 2 * t2y) * 4;
#pragma unroll
      for (int t2x = 0; t2x < 2; t2x++) {
        int ix = qx + bc - t2x;
        if ((unsigned)ix < 64u) {
          int tap = kyo + (1 - bc + 2 * t2x);
          int off = iy * 64 + ix;
#pragma unroll
          for (int ci = 0; ci < 4; ci++) {
            float v = hb[ci * 4096 + off];
            const float* wt = WT + ci * 256 + tap * 16;
#pragma unroll
            for (int co = 0; co < 16; co++) acc[co] = fmaf(v, wt[co], acc[co]);
          }
        }
      }
    }
  }
  int oy = 2 * qy + a, ox = 2 * qx + bc;
  size_t pix = (size_t)b * 16384 + (size_t)(oy * 128 + ox);
  *(float4*)(d1 + 0 * 2097152 + pix * 4) = make_float4(acc[0],  acc[1],  acc[2],  acc[3]);
  *(float4*)(d1 + 1 * 2097152 + pix * 4) = make_float4(acc[4],  acc[5],  acc[6],  acc[7]);
  *(float4*)(d1 + 2 * 2097152 + pix * 4) = make_float4(acc[8],  acc[9],  acc[10], acc[11]);
  *(float4*)(d1 + 3 * 2097152 + pix * 4) = make_float4(acc[12], acc[13], acc[14], acc[15]);
  float vq_[16];
#pragma unroll
  for (int co = 0; co < 16; co++) vq_[co] = acc[co] * acc[co];
  block_stats16(acc, vq_, part, 2048, blockIdx.y * 512 + blockIdx.x);
}

// ---- deconv2: parity-phase compute, g-planar float4 staging, bf16 NHWC out ----
// ---- Output: d2[(b*65536 + oy*256 + ox)*8 + j] = pack(co=2j, co=2j+1), uint ----
__global__ __launch_bounds__(256) void deconv2_t(const float* __restrict__ d1, const float* __restrict__ PF,
                                                 const float* __restrict__ aff, unsigned* __restrict__ d2,
                                                 D2* __restrict__ part) {
  __shared__ float su[16 * 324];
  int t = threadIdx.x, py = t >> 4, px = t & 15;
  int bx = blockIdx.x, bb = bx >> 6, r = bx & 63, tY = r >> 3, tX = r & 7;
  int iy0 = 16 * tY - 1, ix0 = 16 * tX - 1;
  const float4* A4 = (const float4*)aff;
  for (int i = t; i < 1296; i += 256) {
    int g = i / 324, rr = i - g * 324;
    int riy = rr / 18, rix = rr - riy * 18;
    int gy = iy0 + riy, gx = ix0 + rix;
    float4 v = make_float4(0.f, 0.f, 0.f, 0.f);
    if ((unsigned)gy < 128u && (unsigned)gx < 128u)
      v = aff_relu4(*(const float4*)(d1 + (size_t)g * 2097152 +
                                     ((size_t)bb * 16384 + (size_t)(gy * 128 + gx)) * 4),
                    A4[g], A4[4 + g]);
    int s0 = g * 1296 + rr;   // su[(g*4+c4)*324 + rr]
    su[s0] = v.x; su[s0 + 324] = v.y; su[s0 + 648] = v.z; su[s0 + 972] = v.w;
  }
  __syncthreads();
  const float* WT = PF + 10272;   // [ci*256 + tap*16 + co]
  float vs[16], vq[16];
#pragma unroll
  for (int co = 0; co < 16; co++) { vs[co] = 0.f; vq[co] = 0.f; }
#pragma unroll
  for (int a = 0; a < 2; a++) {
#pragma unroll
    for (int bc = 0; bc < 2; bc++) {
      float acc[16];
#pragma unroll
      for (int co = 0; co < 16; co++) acc[co] = PF[9520 + co];
      int base = (py + a) * 18 + (px + bc);
      for (int ci = 0; ci < 16; ci++) {
        const float* sb = su + ci * 324 + base;
        float v00 = sb[0], v01 = sb[1], v10 = sb[18], v11 = sb[19];
        const float* wci = WT + ci * 256;
        const float* w00p = wci + (((3 - a) * 4 + (3 - bc)) << 4);
        const float* w01p = wci + (((3 - a) * 4 + (1 - bc)) << 4);
        const float* w10p = wci + (((1 - a) * 4 + (3 - bc)) << 4);
        const float* w11p = wci + (((1 - a) * 4 + (1 - bc)) << 4);
#pragma unroll
        for (int co = 0; co < 16; co++) {
          float s0 = fmaf(v00, w00p[co], acc[co]);
          float s1 = fmaf(v01, w01p[co], s0);
          float s2 = fmaf(v10, w10p[co], s1);
          acc[co] = fmaf(v11, w11p[co], s2);
        }
      }
      int oy = 32 * tY + 2 * py + a, ox = 32 * tX + 2 * px + bc;
      uint4* dst = (uint4*)(d2 + ((size_t)bb * 65536 + (size_t)oy * 256 + ox) * 8);
      dst[0] = make_uint4(pk2(acc[0], acc[1]),  pk2(acc[2], acc[3]),
                          pk2(acc[4], acc[5]),  pk2(acc[6], acc[7]));
      dst[1] = make_uint4(pk2(acc[8], acc[9]),  pk2(acc[10], acc[11]),
                          pk2(acc[12], acc[13]), pk2(acc[14], acc[15]));
#pragma unroll
      for (int co = 0; co < 16; co++) {
        vs[co] += acc[co];
        vq[co] = fmaf(acc[co], acc[co], vq[co]);
      }
    }
  }
  block_stats16(vs, vq, part, 2048, bx);
}

// ---- deconv3: bf16 NHWC d2, 16x16 input tile -> 32x32 output tile ----
__device__ __forceinline__ int swz(int p, int g) {
  int s = p * 4 + (g ^ (p & 3));       // rotate channel-group by pixel&3
  return s ^ (((p >> 2) & 1) << 2);    // XOR slot bit2 with slot bit4 (involution)
}

__device__ __forceinline__ float4 aff_relu(float4 v, float4 sc, float4 sh) {
  v.x = fmaxf(fmaf(v.x, sc.x, sh.x), 0.f);
  v.y = fmaxf(fmaf(v.y, sc.y, sh.y), 0.f);
  v.z = fmaxf(fmaf(v.z, sc.z, sh.z), 0.f);
  v.w = fmaxf(fmaf(v.w, sc.w, sh.w), 0.f);
  return v;
}

__device__ __forceinline__ void dot4(float& a, float4 v, float4 w) {
  a = fmaf(v.x, w.x, a); a = fmaf(v.y, w.y, a);
  a = fmaf(v.z, w.z, a); a = fmaf(v.w, w.w, a);
}

__global__ __launch_bounds__(256, 4) void deconv3_t(const unsigned* __restrict__ d2, const float* __restrict__ PF,
                                                    const float* __restrict__ aff, const void* __restrict__ x,
                                                    void* __restrict__ outp, double* __restrict__ rp,
                                                    const int* __restrict__ modep) {
  const int m = *modep;
  __shared__ float4 sd4[1296];          // 18*18 pixels * 4 channel-groups, swizzled
  int t = threadIdx.x;
  int bx = blockIdx.x;
  int b = bx >> 8, r = bx & 255, tY = r >> 4, tX = r & 15;   // 16x16 tiles of 16x16 input px
  int iy0 = 16 * tY - 1, ix0 = 16 * tX - 1;
  const float4* A4 = (const float4*)aff;
  float4 SC0 = A4[0], SC1 = A4[1], SC2 = A4[2], SC3 = A4[3];
  float4 SH0 = A4[4], SH1 = A4[5], SH2 = A4[6], SH3 = A4[7];
  const unsigned* db = d2 + (size_t)b * 524288;   // bf16 NHWC, 8 uints/pixel
  for (int p = t; p < 324; p += 256) {
    int riy = p / 18, rix = p - riy * 18;
    int gy = iy0 + riy, gx = ix0 + rix;
    float4 v0, v1, v2, v3;
    if ((unsigned)gy < 256u && (unsigned)gx < 256u) {
      const uint4* s = (const uint4*)(db + ((size_t)gy * 256 + gx) * 8);
      uint4 u0 = s[0], u1 = s[1];
      v0 = aff_relu(make_float4(lo2f(u0.x), hi2f(u0.x), lo2f(u0.y), hi2f(u0.y)), SC0, SH0);
      v1 = aff_relu(make_float4(lo2f(u0.z), hi2f(u0.z), lo2f(u0.w), hi2f(u0.w)), SC1, SH1);
      v2 = aff_relu(make_float4(lo2f(u1.x), hi2f(u1.x), lo2f(u1.y), hi2f(u1.y)), SC2, SH2);
      v3 = aff_relu(make_float4(lo2f(u1.z), hi2f(u1.z), lo2f(u1.w), hi2f(u1.w)), SC3, SH3);
    } else {
      v0 = v1 = v2 = v3 = make_float4(0.f, 0.f, 0.f, 0.f);
    }
    sd4[swz(p, 0)] = v0; sd4[swz(p, 1)] = v1; sd4[swz(p, 2)] = v2; sd4[swz(p, 3)] = v3;
  }
  __syncthreads();

  int lx = t & 15, ly = t >> 4;          // this thread's input pixel within tile
  float bias = PF[9792];
  float a00 = bias, a01 = bias, a10 = bias, a11 = bias;
  const float* WT = PF + 10016;          // [tap*16 + ci], tap = ky*4+kx
  int p00 = ly * 18 + lx;                // LDS pixel index of (dy=-1,dx=-1)
#define TAPW(ky, kx) (*(const float4*)(WT + ((ky) * 4 + (kx)) * 16 + (g << 2)))
#pragma unroll
  for (int g = 0; g < 4; g++) {
    float4 w33 = TAPW(3, 3), w31 = TAPW(3, 1), w32 = TAPW(3, 2), w30 = TAPW(3, 0);
    float4 w13 = TAPW(1, 3), w11 = TAPW(1, 1), w12 = TAPW(1, 2), w10 = TAPW(1, 0);
    float4 w23 = TAPW(2, 3), w21 = TAPW(2, 1), w22 = TAPW(2, 2), w20 = TAPW(2, 0);
    float4 w03 = TAPW(0, 3), w01 = TAPW(0, 1), w02 = TAPW(0, 2), w00 = TAPW(0, 0);
    float4 v;
    v = sd4[swz(p00, g)];      dot4(a00, v, w33);
    v = sd4[swz(p00 + 1, g)];  dot4(a00, v, w31); dot4(a01, v, w32);
    v = sd4[swz(p00 + 2, g)];  dot4(a01, v, w30);
    v = sd4[swz(p00 + 18, g)]; dot4(a00, v, w13); dot4(a10, v, w23);
    v = sd4[swz(p00 + 19, g)]; dot4(a00, v, w11); dot4(a01, v, w12); dot4(a10, v, w21); dot4(a11, v, w22);
    v = sd4[swz(p00 + 20, g)]; dot4(a01, v, w10); dot4(a11, v, w20);
    v = sd4[swz(p00 + 36, g)]; dot4(a10, v, w03);
    v = sd4[swz(p00 + 37, g)]; dot4(a10, v, w01); dot4(a11, v, w02);
    v = sd4[swz(p00 + 38, g)]; dot4(a11, v, w00);
  }
#undef TAPW

  int oy = 32 * tY + 2 * ly, ox = 32 * tX + 2 * lx;
  size_t ob = (size_t)b * 262144 + (size_t)oy * 512 + ox;
  float o0 = 1.f / (1.f + expf(-a00));
  float o1 = 1.f / (1.f + expf(-a01));
  float o2 = 1.f / (1.f + expf(-a10));
  float o3 = 1.f / (1.f + expf(-a11));
  if (m) {
    bf16* op = (bf16*)outp;
    op[ob] = __float2bfloat16(o0);       op[ob + 1] = __float2bfloat16(o1);
    op[ob + 512] = __float2bfloat16(o2); op[ob + 513] = __float2bfloat16(o3);
  } else {
    float* op = (float*)outp;
    op[ob] = o0;       op[ob + 1] = o1;
    op[ob + 512] = o2; op[ob + 513] = o3;
  }
  float d0_ = ldv(x, ob, m) - o0;
  float d1_ = ldv(x, ob + 1, m) - o1;
  float d2_ = ldv(x, ob + 512, m) - o2;
  float d3_ = ldv(x, ob + 513, m) - o3;
  float ds = fmaf(d0_, d0_, fmaf(d1_, d1_, fmaf(d2_, d2_, d3_ * d3_)));
  block_sum1(ds, rp + bx);
}

__global__ __launch_bounds__(256) void finalize_k(const double* __restrict__ vp, const double* __restrict__ rp,
                                                  void* outp, const int* modep) {
  double s = 0, rr = 0;
  for (int i = threadIdx.x; i < 512; i += 256) s += vp[i];
  for (int i = threadIdx.x; i < 8192; i += 256) rr += rp[i];
#pragma unroll
  for (int o = 32; o; o >>= 1) { s += __shfl_down(s, o, 64); rr += __shfl_down(rr, o, 64); }
  __shared__ double l1[4], l2[4];
  int lane = threadIdx.x & 63, w = threadIdx.x >> 6;
  if (lane == 0) { l1[w] = s; l2[w] = rr; }
  __syncthreads();
  if (threadIdx.x == 0) {
    double S = l1[0] + l1[1] + l1[2] + l1[3], R = l2[0] + l2[1] + l2[2] + l2[3];
    double total = R * (1.0 / 8388608.0) + 1.2 * (S * (1.0 / 262144.0));
    if (*modep) ((bf16*)outp)[8388608] = __float2bfloat16((float)total);
    else        ((float*)outp)[8388608] = (float)total;
  }
}

extern "C" void kernel_launch(void* const* d_in, const int* in_sizes, int n_in,
                              void* d_out, int out_size, void* d_ws, size_t ws_size,
                              hipStream_t stream) {
  const void* x    = d_in[0];
  const void* w1   = d_in[1];  const void* b1  = d_in[2];
  const void* g1   = d_in[3];  const void* be1 = d_in[4];
  const void* w2   = d_in[5];  const void* b2  = d_in[6];
  const void* g2   = d_in[7];  const void* be2 = d_in[8];
  const void* w3   = d_in[9];  const void* b3  = d_in[10];
  const void* g3   = d_in[11]; const void* be3 = d_in[12];
  const void* wpre = d_in[13]; const void* bpre= d_in[14];
  const void* cbk  = d_in[15];
  const void* wpost= d_in[16]; const void* bpost= d_in[17];
  const void* wd1  = d_in[18]; const void* bd1 = d_in[19];
  const void* g4   = d_in[20]; const void* be4 = d_in[21];
  const void* wd2  = d_in[22]; const void* bd2 = d_in[23];
  const void* g5   = d_in[24]; const void* be5 = d_in[25];
  const void* wd3  = d_in[26]; const void* bd3 = d_in[27];

  char* ws = (char*)d_ws;
  int*    MODE = (int*)ws;
  float*  STF  = (float*)(ws + 1024);      // 5 layers x 32 f
  double* STD  = (double*)(ws + 4096);     // 5 layers x 32 d
  float*  PF   = (float*)(ws + 8192);
  double* PD   = (double*)(ws + 73728);
  D2*     P1   = (D2*)(ws + 131072);       // 16*8192
  D2*     P2   = (D2*)(ws + 2228224);      // 16*2048
  D2*     P3   = (D2*)(ws + 2752512);      // 4*512
  D2*     P4   = (D2*)(ws + 2785280);      // 16*2048
  D2*     P5   = (D2*)(ws + 3309568);      // 16*2048
  double* VP   = (double*)(ws + 3833856);  // 512
  double* RP   = (double*)(ws + 3837952);  // 8192
  char* HB = ws + 6291456;
  float*    H1  = (float*)HB;                     // 134 MB, 4 g-planes of 32 MB
  float*    H2  = (float*)(HB + 134217728);       // 33.5 MB
  double*   C3  = (double*)HB;                    // 4 MB, reuses dead H1
  float*    D0  = (float*)(HB + 165675008);       // 2 MB, inside dead H2
  float*    D1  = (float*)HB;                     // 32 MB, 4 g-planes, reuses dead C3
  unsigned* D2T = (unsigned*)(HB + 33554432);     // 67 MB bf16 NHWC, after D1

  prep_k<<<1, 256, 0, stream>>>((const unsigned*)x, MODE,
                                w1, b1, w2, b2, w3, b3, wpre, bpre, cbk, wpost, bpost,
                                wd1, bd1, wd2, bd2, wd3, bd3,
                                g1, be1, g2, be2, g3, be3, g4, be4, g5, be5, PF, PD);

  conv1_t<<<8192, 256, 0, stream>>>(x, PF, H1, P1, MODE);
  bn_reduce_k<<<16, 256, 0, stream>>>(P1, 8192, STD + 0, STF + 0, PF + 9856, 1.0 / 2097152.0);

  conv2_t<<<2048, 256, 0, stream>>>(H1, PF, STF + 0, H2, P2);
  bn_reduce_k<<<16, 256, 0, stream>>>(P2, 2048, STD + 32, STF + 32, PF + 9888, 1.0 / 524288.0);

  conv3_k<<<512, 256, 0, stream>>>(H2, PD, STF + 32, C3, P3);
  bn_reduce_k<<<4, 256, 0, stream>>>(P3, 512, STD + 64, STF + 64, PF + 9920, 1.0 / 131072.0);

  vq_k<<<512, 256, 0, stream>>>(C3, PD, STD + 64, D0, VP);

  deconv1_k<<<dim3(512, 4), 256, 0, stream>>>(D0, PF, D1, P4);
  bn_reduce_k<<<16, 256, 0, stream>>>(P4, 2048, STD + 96, STF + 96, PF + 9952, 1.0 / 524288.0);

  deconv2_t<<<2048, 256, 0, stream>>>(D1, PF, STF + 96, D2T, P5);
  bn_reduce_k<<<16, 256, 0, stream>>>(P5, 2048, STD + 128, STF + 128, PF + 9984, 1.0 / 2097152.0);

  deconv3_t<<<8192, 256, 0, stream>>>(D2T, PF, STF + 128, x, d_out, RP, MODE);
  finalize_k<<<1, 256, 0, stream>>>(VP, RP, d_out, MODE);
}

// Round 8
// 539.353 us; speedup vs baseline: 1.2964x; 1.2964x over previous
//
#include <hip/hip_runtime.h>
#include <hip/hip_bf16.h>
#include <math.h>

using bf16 = __hip_bfloat16;

__device__ __forceinline__ float b2f(bf16 v) { return __bfloat162float(v); }
// mode: 1 = inputs bf16, 0 = inputs f32
__device__ __forceinline__ float ldv(const void* p, size_t i, int m) {
  return m ? b2f(((const bf16*)p)[i]) : ((const float*)p)[i];
}

struct D2 { double s, s2; };

// ---- block reductions (blockDim == 256), non-atomic partial writes ----
__device__ __forceinline__ void block_stats1(float v, D2* slot) {
  float v2 = v * v;
#pragma unroll
  for (int o = 32; o; o >>= 1) { v += __shfl_down(v, o, 64); v2 += __shfl_down(v2, o, 64); }
  __shared__ float a1[4], a2[4];
  int lane = threadIdx.x & 63, w = threadIdx.x >> 6;
  if (lane == 0) { a1[w] = v; a2[w] = v2; }
  __syncthreads();
  if (threadIdx.x == 0) {
    slot->s  = (double)a1[0] + a1[1] + a1[2] + a1[3];
    slot->s2 = (double)a2[0] + a2[1] + a2[2] + a2[3];
  }
}

// 4 doubles at once (single barrier, no cross-call race)
__device__ __forceinline__ void block_stats1d4(const double* v, const double* vq, D2* base, int NB, int bx) {
  __shared__ double q1[16], q2[16];
  int lane = threadIdx.x & 63, w = threadIdx.x >> 6;
#pragma unroll
  for (int k = 0; k < 4; k++) {
    double s = v[k], s2 = vq[k];
#pragma unroll
    for (int o = 32; o; o >>= 1) { s += __shfl_down(s, o, 64); s2 += __shfl_down(s2, o, 64); }
    if (lane == 0) { q1[k * 4 + w] = s; q2[k * 4 + w] = s2; }
  }
  __syncthreads();
  if (threadIdx.x < 4) {
    int k = threadIdx.x;
    base[k * NB + bx].s  = q1[k * 4] + q1[k * 4 + 1] + q1[k * 4 + 2] + q1[k * 4 + 3];
    base[k * NB + bx].s2 = q2[k * 4] + q2[k * 4 + 1] + q2[k * 4 + 2] + q2[k * 4 + 3];
  }
}

__device__ __forceinline__ void block_sum1(float v, double* slot) {
#pragma unroll
  for (int o = 32; o; o >>= 1) v += __shfl_down(v, o, 64);
  __shared__ float a1[4];
  int lane = threadIdx.x & 63, w = threadIdx.x >> 6;
  if (lane == 0) a1[w] = v;
  __syncthreads();
  if (threadIdx.x == 0) *slot = (double)a1[0] + a1[1] + a1[2] + a1[3];
}

// 16-channel block stats -> part[co*NB + bx]
__device__ __forceinline__ void block_stats16(const float* vs, const float* vq, D2* base, int NB, int bx) {
  __shared__ float s1[64], s2[64];
  int lane = threadIdx.x & 63, w = threadIdx.x >> 6;
#pragma unroll
  for (int co = 0; co < 16; co++) {
    float v = vs[co], v2 = vq[co];
#pragma unroll
    for (int o = 32; o; o >>= 1) { v += __shfl_down(v, o, 64); v2 += __shfl_down(v2, o, 64); }
    if (lane == 0) { s1[co * 4 + w] = v; s2[co * 4 + w] = v2; }
  }
  __syncthreads();
  if (threadIdx.x < 16) {
    int co = threadIdx.x;
    base[co * NB + bx].s  = (double)s1[co * 4] + s1[co * 4 + 1] + s1[co * 4 + 2] + s1[co * 4 + 3];
    base[co * NB + bx].s2 = (double)s2[co * 4] + s2[co * 4 + 1] + s2[co * 4 + 2] + s2[co * 4 + 3];
  }
}

// PF float layout: W1 0(256) B1 256(16)
//   W2N 272(4096,[cig*1024+tap*64+c4*16+co])  <- conv2 pass-major layout
//   B2 4368(16)
//   WD1 4384(1024, legacy) BD1 5408(16) WD2 5424(4096, legacy)
//   BD2 9520(16) WD3 9536(256, legacy) BD3 9792(1) G/BE 9856+l*32 (gamma 16, beta 16)
//   WD3T 10016(256,[tap*16+ci])   <- tap-major copy for deconv3
//   WD2T 10272(4096,[ci*256+tap*16+co]) <- co-contiguous per (ci,tap) for deconv2
//   WD1T 14368(1024,[ci*256+tap*16+co]) <- co-contiguous per (ci,tap) for deconv1
// PD double layout: W3 0(1024,[co*256+ci*16+tap]) B3 1024(4) WPRE 1028(8) BPRE 1036(2)
//   CB 1040(512) WPOST 1552(8) BPOST 1560(4)
__global__ void prep_k(const unsigned* __restrict__ xw, int* __restrict__ MODE,
                       const void* w1, const void* b1, const void* w2, const void* b2,
                       const void* w3, const void* b3, const void* wpre, const void* bpre,
                       const void* cbk, const void* wpost, const void* bpost,
                       const void* wd1, const void* bd1, const void* wd2, const void* bd2,
                       const void* wd3, const void* bd3,
                       const void* g1, const void* be1, const void* g2, const void* be2,
                       const void* g3, const void* be3, const void* g4, const void* be4,
                       const void* g5, const void* be5,
                       float* __restrict__ PF, double* __restrict__ PD) {
  int t = threadIdx.x;
  // ---- dtype detect (merged init) ----
  __shared__ int smode;
  {
    unsigned lo = xw[t] & 0xFFFFu;
    int inr = (lo >= 0x3000u && lo < 0x4000u) ? 1 : 0;
    unsigned long long b = __ballot(inr);
    __shared__ int cnt[4];
    if ((t & 63) == 0) cnt[t >> 6] = __popcll(b);
    __syncthreads();
    if (t == 0) { smode = (cnt[0] + cnt[1] + cnt[2] + cnt[3] >= 128) ? 1 : 0; *MODE = smode; }
    __syncthreads();
  }
  int m = smode;
  for (int i = t; i < 256; i += 256) PF[i] = ldv(w1, i, m);
  if (t < 16) PF[256 + t] = ldv(b1, t, m);
  for (int i = t; i < 4096; i += 256) {   // w2 (16,16,4,4) -> [cig*1024+tap*64+c4*16+co]
    int cig = i >> 10, tap = (i >> 6) & 15, c4 = (i >> 4) & 3, co = i & 15;
    PF[272 + i] = ldv(w2, co * 256 + (cig * 4 + c4) * 16 + tap, m);
  }
  if (t < 16) PF[4368 + t] = ldv(b2, t, m);
  for (int i = t; i < 1024; i += 256) {   // wd1 (4,16,4,4) -> [co*64+ci*16+tap] (legacy)
    int co = i >> 6, ci = (i >> 4) & 3, tap = i & 15;
    PF[4384 + i] = ldv(wd1, ci * 256 + co * 16 + tap, m);
  }
  for (int i = t; i < 1024; i += 256) {   // wd1 -> [ci*256+tap*16+co]
    int ci = i >> 8, tap = (i >> 4) & 15, co = i & 15;
    PF[14368 + i] = ldv(wd1, ci * 256 + co * 16 + tap, m);
  }
  if (t < 16) PF[5408 + t] = ldv(bd1, t, m);
  for (int i = t; i < 4096; i += 256) {   // wd2 legacy
    int co = i >> 8, ci = (i >> 4) & 15, tap = i & 15;
    PF[5424 + i] = ldv(wd2, ci * 256 + co * 16 + tap, m);
  }
  for (int i = t; i < 4096; i += 256) {   // wd2 -> [ci*256+tap*16+co]
    int ci = i >> 8, tap = (i >> 4) & 15, co = i & 15;
    PF[10272 + i] = ldv(wd2, ci * 256 + co * 16 + tap, m);
  }
  if (t < 16) PF[9520 + t] = ldv(bd2, t, m);
  for (int i = t; i < 256; i += 256) PF[9536 + i] = ldv(wd3, i, m);
  {   // tap-major wd3: WT[tap*16 + ci] = wd3[ci*16 + tap]
    int tap = t >> 4, ci = t & 15;
    PF[10016 + t] = ldv(wd3, ci * 16 + tap, m);
  }
  if (t == 0) PF[9792] = ldv(bd3, 0, m);
  if (t < 16) {
    PF[9856 + t] = ldv(g1, t, m);  PF[9872 + t] = ldv(be1, t, m);
    PF[9888 + t] = ldv(g2, t, m);  PF[9904 + t] = ldv(be2, t, m);
    PF[9952 + t] = ldv(g4, t, m);  PF[9968 + t] = ldv(be4, t, m);
    PF[9984 + t] = ldv(g5, t, m);  PF[10000 + t] = ldv(be5, t, m);
  }
  if (t < 4) { PF[9920 + t] = ldv(g3, t, m); PF[9936 + t] = ldv(be3, t, m); }
  for (int i = t; i < 1024; i += 256) PD[i] = ldv(w3, i, m);
  if (t < 4) PD[1024 + t] = ldv(b3, t, m);
  if (t < 8) PD[1028 + t] = ldv(wpre, t, m);
  if (t < 2) PD[1036 + t] = ldv(bpre, t, m);
  for (int i = t; i < 512; i += 256) PD[1040 + i] = ldv(cbk, i, m);
  if (t < 8) PD[1552 + t] = ldv(wpost, t, m);
  if (t < 4) PD[1560 + t] = ldv(bpost, t, m);
}

// ---- BN reduce: partials -> scale/shift (f64 + f32) ----
__global__ __launch_bounds__(256) void bn_reduce_k(const D2* __restrict__ part, int NB,
                                                   double* __restrict__ stD, float* __restrict__ stF,
                                                   const float* __restrict__ gb, double invN) {
  int c = blockIdx.x;
  double s = 0, s2 = 0;
  for (int i = threadIdx.x; i < NB; i += 256) { D2 p = part[c * NB + i]; s += p.s; s2 += p.s2; }
#pragma unroll
  for (int o = 32; o; o >>= 1) { s += __shfl_down(s, o, 64); s2 += __shfl_down(s2, o, 64); }
  __shared__ double l1[4], l2[4];
  int lane = threadIdx.x & 63, w = threadIdx.x >> 6;
  if (lane == 0) { l1[w] = s; l2[w] = s2; }
  __syncthreads();
  if (threadIdx.x == 0) {
    double S = l1[0] + l1[1] + l1[2] + l1[3], Q = l2[0] + l2[1] + l2[2] + l2[3];
    double mu = S * invN, var = Q * invN - mu * mu;
    if (var < 0) var = 0;
    double sc = (double)gb[c] / sqrt(var + 1e-5);
    double sh = (double)gb[16 + c] - mu * sc;
    stD[c] = sc; stD[16 + c] = sh;
    stF[c] = (float)sc; stF[16 + c] = (float)sh;
  }
}

// ---- conv1 tiled: 64x4 tile, all 16 co per block, x staged once in LDS ----
// Output H1 is channel-group planar: plane g (g=co>>2) is [b][y][x][4],
// plane stride 8388608 floats (32 MB). Pixel index pix=(b*65536+oy*256+ox).
__global__ __launch_bounds__(256) void conv1_t(const void* __restrict__ x, const float* __restrict__ PF,
                                               float* __restrict__ y, D2* __restrict__ part,
                                               const int* modep) {
  const int m = *modep;
  __shared__ float sx[10 * 130];
  int t = threadIdx.x;
  int bx = blockIdx.x;
  int b = bx >> 8, r = bx & 255, tY = r >> 2, tX = r & 3;   // 64 tY x 4 tX tiles of 64x4
  int iy0 = 8 * tY - 1, ix0 = 128 * tX - 1;
  size_t xb = (size_t)b * 262144;
  for (int i = t; i < 1300; i += 256) {
    int ry = i / 130, rx = i - ry * 130;
    int gy = iy0 + ry, gx = ix0 + rx;
    float v = 0.f;
    if ((unsigned)gy < 512u && (unsigned)gx < 512u) v = ldv(x, xb + (size_t)gy * 512 + gx, m);
    sx[i] = v;
  }
  __syncthreads();
  int tyy = t >> 6, txx = t & 63;
  int oy = tY * 4 + tyy, ox = tX * 64 + txx;
  float acc[16];
#pragma unroll
  for (int co = 0; co < 16; co++) acc[co] = PF[256 + co];
  int ly = 2 * tyy, lx = 2 * txx;
#pragma unroll
  for (int ky = 0; ky < 4; ky++) {
#pragma unroll
    for (int kx = 0; kx < 4; kx++) {
      float v = sx[(ly + ky) * 130 + lx + kx];
#pragma unroll
      for (int co = 0; co < 16; co++) acc[co] = fmaf(v, PF[co * 16 + ky * 4 + kx], acc[co]);
    }
  }
  size_t pix = (size_t)b * 65536 + (size_t)(oy * 256 + ox);
  *(float4*)(y + 0 * 8388608 + pix * 4) = make_float4(acc[0],  acc[1],  acc[2],  acc[3]);
  *(float4*)(y + 1 * 8388608 + pix * 4) = make_float4(acc[4],  acc[5],  acc[6],  acc[7]);
  *(float4*)(y + 2 * 8388608 + pix * 4) = make_float4(acc[8],  acc[9],  acc[10], acc[11]);
  *(float4*)(y + 3 * 8388608 + pix * 4) = make_float4(acc[12], acc[13], acc[14], acc[15]);
  float vq_[16];
#pragma unroll
  for (int co = 0; co < 16; co++) vq_[co] = acc[co] * acc[co];
  block_stats16(acc, vq_, part, 8192, bx);
}

// ---- conv2: g-planar input, 4 passes of 4 ci each, async-stage prefetch.
// ---- OOB halo stages EXACT ZERO (affine only in-bounds).
__device__ __forceinline__ float4 aff_relu4(float4 v, float4 sc, float4 sh) {
  v.x = fmaxf(fmaf(v.x, sc.x, sh.x), 0.f);
  v.y = fmaxf(fmaf(v.y, sc.y, sh.y), 0.f);
  v.z = fmaxf(fmaf(v.z, sc.z, sh.z), 0.f);
  v.w = fmaxf(fmaf(v.w, sc.w, sh.w), 0.f);
  return v;
}

__global__ __launch_bounds__(256, 6) void conv2_t(const float* __restrict__ h1, const float* __restrict__ PF,
                                                  const float* __restrict__ aff, float* __restrict__ h2,
                                                  D2* __restrict__ part) {
  __shared__ float su[4896];   // [q][plane][34][18]
  int t = threadIdx.x, ty = t >> 4, tx = t & 15;
  int bx = blockIdx.x, bb = bx >> 6, r = bx & 63, tY = r >> 3, tX = r & 7;
  int oy = tY * 16 + ty, ox = tX * 16 + tx;
  int iy0 = 32 * tY - 1, ix0 = 32 * tX - 1;
  const float* W2 = PF + 272;              // [cig*1024 + tap*64 + c4*16 + co]
  const float4* A4 = (const float4*)aff;
  // precompute staging geometry (same for all g)
  int goff[5], soff[5];
#pragma unroll
  for (int k = 0; k < 5; k++) {
    int i = t + k * 256;
    goff[k] = -1; soff[k] = -1;
    if (i < 1156) {
      int riy = i / 34, rix = i - riy * 34;
      int gy = iy0 + riy, gx = ix0 + rix;
      soff[k] = (rix & 1) * 2448 + riy * 18 + (rix >> 1);
      if ((unsigned)gy < 256u && (unsigned)gx < 256u) goff[k] = (gy * 256 + gx) * 4;
    }
  }
  const float* pb = h1 + (size_t)bb * 262144;
  float4 rv[5];
#pragma unroll
  for (int k = 0; k < 5; k++) {
    float4 v = make_float4(0.f, 0.f, 0.f, 0.f);
    if (goff[k] >= 0) v = *(const float4*)(pb + goff[k]);
    rv[k] = v;
  }
  float acc[16];
#pragma unroll
  for (int co = 0; co < 16; co++) acc[co] = PF[4368 + co];
#pragma unroll
  for (int g = 0; g < 4; g++) {
    float4 SC = A4[g], SH = A4[4 + g];
    __syncthreads();
#pragma unroll
    for (int k = 0; k < 5; k++) {
      if (soff[k] >= 0) {
        float4 v = make_float4(0.f, 0.f, 0.f, 0.f);
        if (goff[k] >= 0) v = aff_relu4(rv[k], SC, SH);   // affine ONLY in-bounds; pad stays 0
        int s = soff[k];
        su[s] = v.x; su[612 + s] = v.y; su[1224 + s] = v.z; su[1836 + s] = v.w;
      }
    }
    __syncthreads();
    if (g < 3) {
      const float* pg = pb + (size_t)(g + 1) * 8388608;
#pragma unroll
      for (int k = 0; k < 5; k++) {
        float4 v = make_float4(0.f, 0.f, 0.f, 0.f);
        if (goff[k] >= 0) v = *(const float4*)(pg + goff[k]);
        rv[k] = v;
      }
    }
    const float* wg = W2 + g * 1024;
    int base = 2 * ty * 18 + tx;
#pragma unroll
    for (int ky = 0; ky < 4; ky++) {
#pragma unroll
      for (int kx = 0; kx < 4; kx++) {
        int s = (kx & 1) * 2448 + ky * 18 + (kx >> 1) + base;
        float v0 = su[s], v1 = su[612 + s], v2 = su[1224 + s], v3 = su[1836 + s];
        const float* wt = wg + (ky * 4 + kx) * 64;
#pragma unroll
        for (int co = 0; co < 16; co++) {
          float s0 = fmaf(v0, wt[co], acc[co]);
          float s1 = fmaf(v1, wt[16 + co], s0);
          float s2 = fmaf(v2, wt[32 + co], s1);
          acc[co] = fmaf(v3, wt[48 + co], s2);
        }
      }
    }
  }
  float vq_[16];
#pragma unroll
  for (int co = 0; co < 16; co++) {
    h2[((size_t)(bb * 16 + co) * 128 + oy) * 128 + ox] = acc[co];
    vq_[co] = acc[co] * acc[co];
  }
  block_stats16(acc, vq_, part, 2048, bx);
}

// ---- conv3: all 4 co per thread; f32 h2 (affine2+relu) -> f64 raw (32,4,64,64) ----
__global__ __launch_bounds__(256) void conv3_k(const float* __restrict__ h2, const double* __restrict__ PD,
                                               const float* __restrict__ aff, double* __restrict__ c3,
                                               D2* __restrict__ part) {
  int idx = blockIdx.x * 256 + threadIdx.x;   // 131072
  int b = idx >> 12, rem = idx & 4095, oy = rem >> 6, ox = rem & 63;
  double a0 = PD[1024], a1 = PD[1025], a2 = PD[1026], a3 = PD[1027];
  int iy0 = 2 * oy - 1, ix0 = 2 * ox - 1;
  for (int ci = 0; ci < 16; ci++) {
    const float* ib = h2 + (size_t)(b * 16 + ci) * 16384;
    float sc = aff[ci], sh = aff[16 + ci];
    const double* wr = PD + ci * 16;   // + co*256 per output
#pragma unroll
    for (int ky = 0; ky < 4; ky++) {
      int iy = iy0 + ky;
      if ((unsigned)iy < 128u) {
        const float* row = ib + iy * 128;
#pragma unroll
        for (int kx = 0; kx < 4; kx++) {
          int ix = ix0 + kx;
          if ((unsigned)ix < 128u) {
            double v = (double)fmaxf(fmaf(row[ix], sc, sh), 0.f);
            int tp = ky * 4 + kx;
            a0 = fma(v, wr[tp], a0);
            a1 = fma(v, wr[256 + tp], a1);
            a2 = fma(v, wr[512 + tp], a2);
            a3 = fma(v, wr[768 + tp], a3);
          }
        }
      }
    }
  }
  size_t cb = (size_t)b * 16384 + rem;
  c3[cb] = a0; c3[cb + 4096] = a1; c3[cb + 8192] = a2; c3[cb + 12288] = a3;
  double vs[4] = {a0, a1, a2, a3};
  double vq[4] = {a0 * a0, a1 * a1, a2 * a2, a3 * a3};
  block_stats1d4(vs, vq, part, 512, blockIdx.x);
}

// ---- VQ: f64 BN3 affine+relu -> wpre -> argmin -> wpost -> d0 (f32) ----
__global__ __launch_bounds__(256) void vq_k(const double* __restrict__ c3, const double* __restrict__ PD,
                                            const double* __restrict__ stD2, float* __restrict__ d0,
                                            double* __restrict__ vp) {
  __shared__ double cb[512];
  for (int i = threadIdx.x; i < 512; i += 256) cb[i] = PD[1040 + i];
  __syncthreads();
  int pix = blockIdx.x * 256 + threadIdx.x;
  int b = pix >> 12, rem = pix & 4095;
  const double* hb = c3 + (size_t)b * 16384 + rem;
  double q0 = PD[1036], q1 = PD[1037];
#pragma unroll
  for (int ci = 0; ci < 4; ci++) {
    double v = fma(hb[ci * 4096], stD2[ci], stD2[16 + ci]);
    if (v < 0) v = 0;
    q0 = fma(v, PD[1028 + ci], q0);
    q1 = fma(v, PD[1032 + ci], q1);
  }
  int best = 0;
  double bd = 1e300;
  for (int k = 0; k < 256; k++) {
    double dx = q0 - cb[2 * k], dy = q1 - cb[2 * k + 1];
    double d = dx * dx + dy * dy;
    if (d < bd) { bd = d; best = k; }   // strict < == first-index argmin
  }
  double c0 = cb[2 * best], c1 = cb[2 * best + 1];
  double e0 = q0 - c0, e1 = q1 - c1;
  float* ob = d0 + (size_t)b * 16384 + rem;
#pragma unroll
  for (int c = 0; c < 4; c++)
    ob[c * 4096] = (float)(PD[1560 + c] + PD[1552 + 2 * c] * c0 + PD[1552 + 2 * c + 1] * c1);
  double v = e0 * e0 + e1 * e1;
#pragma unroll
  for (int o = 32; o; o >>= 1) v += __shfl_down(v, o, 64);
  __shared__ double l1[4];
  int lane = threadIdx.x & 63, w = threadIdx.x >> 6;
  if (lane == 0) l1[w] = v;
  __syncthreads();
  if (threadIdx.x == 0) vp[blockIdx.x] = l1[0] + l1[1] + l1[2] + l1[3];
}

// ---- deconv1: parity-phase grid (512, phase). d1 g-planar f32. ----
__global__ __launch_bounds__(256) void deconv1_k(const float* __restrict__ d0, const float* __restrict__ PF,
                                                 float* __restrict__ d1, D2* __restrict__ part) {
  int phase = blockIdx.y, a = phase >> 1, bc = phase & 1;
  int idx = blockIdx.x * 256 + threadIdx.x;   // 131072 quads
  int b = idx >> 12, rem = idx & 4095, qy = rem >> 6, qx = rem & 63;
  const float* WT = PF + 14368;   // [ci*256 + tap*16 + co]
  float acc[16];
#pragma unroll
  for (int co = 0; co < 16; co++) acc[co] = PF[5408 + co];
  const float* hb = d0 + (size_t)b * 16384;
#pragma unroll
  for (int t2y = 0; t2y < 2; t2y++) {
    int iy = qy + a - t2y;
    if ((unsigned)iy < 64u) {
      int kyo = (1 - a + 2 * t2y) * 4;
#pragma unroll
      for (int t2x = 0; t2x < 2; t2x++) {
        int ix = qx + bc - t2x;
        if ((unsigned)ix < 64u) {
          int tap = kyo + (1 - bc + 2 * t2x);
          int off = iy * 64 + ix;
#pragma unroll
          for (int ci = 0; ci < 4; ci++) {
            float v = hb[ci * 4096 + off];
            const float* wt = WT + ci * 256 + tap * 16;
#pragma unroll
            for (int co = 0; co < 16; co++) acc[co] = fmaf(v, wt[co], acc[co]);
          }
        }
      }
    }
  }
  int oy = 2 * qy + a, ox = 2 * qx + bc;
  size_t pix = (size_t)b * 16384 + (size_t)(oy * 128 + ox);
  *(float4*)(d1 + 0 * 2097152 + pix * 4) = make_float4(acc[0],  acc[1],  acc[2],  acc[3]);
  *(float4*)(d1 + 1 * 2097152 + pix * 4) = make_float4(acc[4],  acc[5],  acc[6],  acc[7]);
  *(float4*)(d1 + 2 * 2097152 + pix * 4) = make_float4(acc[8],  acc[9],  acc[10], acc[11]);
  *(float4*)(d1 + 3 * 2097152 + pix * 4) = make_float4(acc[12], acc[13], acc[14], acc[15]);
  float vq_[16];
#pragma unroll
  for (int co = 0; co < 16; co++) vq_[co] = acc[co] * acc[co];
  block_stats16(acc, vq_, part, 2048, blockIdx.y * 512 + blockIdx.x);
}

// ---- deconv2: parity-phase compute, g-planar float4 staging, f32 NHWC out ----
// ---- Output NHWC: d2[((b*65536 + oy*256 + ox)*16) + co]
__global__ __launch_bounds__(256) void deconv2_t(const float* __restrict__ d1, const float* __restrict__ PF,
                                                 const float* __restrict__ aff, float* __restrict__ d2,
                                                 D2* __restrict__ part) {
  __shared__ float su[16 * 324];
  int t = threadIdx.x, py = t >> 4, px = t & 15;
  int bx = blockIdx.x, bb = bx >> 6, r = bx & 63, tY = r >> 3, tX = r & 7;
  int iy0 = 16 * tY - 1, ix0 = 16 * tX - 1;
  const float4* A4 = (const float4*)aff;
  for (int i = t; i < 1296; i += 256) {
    int g = i / 324, rr = i - g * 324;
    int riy = rr / 18, rix = rr - riy * 18;
    int gy = iy0 + riy, gx = ix0 + rix;
    float4 v = make_float4(0.f, 0.f, 0.f, 0.f);
    if ((unsigned)gy < 128u && (unsigned)gx < 128u)
      v = aff_relu4(*(const float4*)(d1 + (size_t)g * 2097152 +
                                     ((size_t)bb * 16384 + (size_t)(gy * 128 + gx)) * 4),
                    A4[g], A4[4 + g]);
    int s0 = g * 1296 + rr;   // su[(g*4+c4)*324 + rr]
    su[s0] = v.x; su[s0 + 324] = v.y; su[s0 + 648] = v.z; su[s0 + 972] = v.w;
  }
  __syncthreads();
  const float* WT = PF + 10272;   // [ci*256 + tap*16 + co]
  float vs[16], vq[16];
#pragma unroll
  for (int co = 0; co < 16; co++) { vs[co] = 0.f; vq[co] = 0.f; }
#pragma unroll
  for (int a = 0; a < 2; a++) {
#pragma unroll
    for (int bc = 0; bc < 2; bc++) {
      float acc[16];
#pragma unroll
      for (int co = 0; co < 16; co++) acc[co] = PF[9520 + co];
      int base = (py + a) * 18 + (px + bc);
      for (int ci = 0; ci < 16; ci++) {
        const float* sb = su + ci * 324 + base;
        float v00 = sb[0], v01 = sb[1], v10 = sb[18], v11 = sb[19];
        const float* wci = WT + ci * 256;
        const float* w00p = wci + (((3 - a) * 4 + (3 - bc)) << 4);
        const float* w01p = wci + (((3 - a) * 4 + (1 - bc)) << 4);
        const float* w10p = wci + (((1 - a) * 4 + (3 - bc)) << 4);
        const float* w11p = wci + (((1 - a) * 4 + (1 - bc)) << 4);
#pragma unroll
        for (int co = 0; co < 16; co++) {
          float s0 = fmaf(v00, w00p[co], acc[co]);
          float s1 = fmaf(v01, w01p[co], s0);
          float s2 = fmaf(v10, w10p[co], s1);
          acc[co] = fmaf(v11, w11p[co], s2);
        }
      }
      int oy = 32 * tY + 2 * py + a, ox = 32 * tX + 2 * px + bc;
      float4* dst = (float4*)(d2 + ((size_t)bb * 65536 + (size_t)oy * 256 + ox) * 16);
      dst[0] = make_float4(acc[0],  acc[1],  acc[2],  acc[3]);
      dst[1] = make_float4(acc[4],  acc[5],  acc[6],  acc[7]);
      dst[2] = make_float4(acc[8],  acc[9],  acc[10], acc[11]);
      dst[3] = make_float4(acc[12], acc[13], acc[14], acc[15]);
#pragma unroll
      for (int co = 0; co < 16; co++) {
        vs[co] += acc[co];
        vq[co] = fmaf(acc[co], acc[co], vq[co]);
      }
    }
  }
  block_stats16(vs, vq, part, 2048, bx);
}

// ---- deconv3: f32 NHWC d2, 16x16 input tile -> 32x32 output tile ----
__device__ __forceinline__ int swz(int p, int g) {
  int s = p * 4 + (g ^ (p & 3));       // rotate channel-group by pixel&3
  return s ^ (((p >> 2) & 1) << 2);    // XOR slot bit2 with slot bit4 (involution)
}

__device__ __forceinline__ float4 aff_relu(float4 v, float4 sc, float4 sh) {
  v.x = fmaxf(fmaf(v.x, sc.x, sh.x), 0.f);
  v.y = fmaxf(fmaf(v.y, sc.y, sh.y), 0.f);
  v.z = fmaxf(fmaf(v.z, sc.z, sh.z), 0.f);
  v.w = fmaxf(fmaf(v.w, sc.w, sh.w), 0.f);
  return v;
}

__device__ __forceinline__ void dot4(float& a, float4 v, float4 w) {
  a = fmaf(v.x, w.x, a); a = fmaf(v.y, w.y, a);
  a = fmaf(v.z, w.z, a); a = fmaf(v.w, w.w, a);
}

__global__ __launch_bounds__(256, 4) void deconv3_t(const float* __restrict__ d2, const float* __restrict__ PF,
                                                    const float* __restrict__ aff, const void* __restrict__ x,
                                                    void* __restrict__ outp, double* __restrict__ rp,
                                                    const int* __restrict__ modep) {
  const int m = *modep;
  __shared__ float4 sd4[1296];          // 18*18 pixels * 4 channel-groups, swizzled
  int t = threadIdx.x;
  int bx = blockIdx.x;
  int b = bx >> 8, r = bx & 255, tY = r >> 4, tX = r & 15;   // 16x16 tiles of 16x16 input px
  int iy0 = 16 * tY - 1, ix0 = 16 * tX - 1;
  const float4* A4 = (const float4*)aff;
  float4 SC0 = A4[0], SC1 = A4[1], SC2 = A4[2], SC3 = A4[3];
  float4 SH0 = A4[4], SH1 = A4[5], SH2 = A4[6], SH3 = A4[7];
  const float* db = d2 + (size_t)b * 1048576;   // NHWC, 256*256*16 per batch
  for (int p = t; p < 324; p += 256) {
    int riy = p / 18, rix = p - riy * 18;
    int gy = iy0 + riy, gx = ix0 + rix;
    float4 v0, v1, v2, v3;
    if ((unsigned)gy < 256u && (unsigned)gx < 256u) {
      const float4* s = (const float4*)(db + ((size_t)gy * 256 + gx) * 16);
      v0 = aff_relu(s[0], SC0, SH0);
      v1 = aff_relu(s[1], SC1, SH1);
      v2 = aff_relu(s[2], SC2, SH2);
      v3 = aff_relu(s[3], SC3, SH3);
    } else {
      v0 = v1 = v2 = v3 = make_float4(0.f, 0.f, 0.f, 0.f);
    }
    sd4[swz(p, 0)] = v0; sd4[swz(p, 1)] = v1; sd4[swz(p, 2)] = v2; sd4[swz(p, 3)] = v3;
  }
  __syncthreads();

  int lx = t & 15, ly = t >> 4;          // this thread's input pixel within tile
  float bias = PF[9792];
  float a00 = bias, a01 = bias, a10 = bias, a11 = bias;
  const float* WT = PF + 10016;          // [tap*16 + ci], tap = ky*4+kx
  int p00 = ly * 18 + lx;                // LDS pixel index of (dy=-1,dx=-1)
#define TAPW(ky, kx) (*(const float4*)(WT + ((ky) * 4 + (kx)) * 16 + (g << 2)))
#pragma unroll
  for (int g = 0; g < 4; g++) {
    float4 w33 = TAPW(3, 3), w31 = TAPW(3, 1), w32 = TAPW(3, 2), w30 = TAPW(3, 0);
    float4 w13 = TAPW(1, 3), w11 = TAPW(1, 1), w12 = TAPW(1, 2), w10 = TAPW(1, 0);
    float4 w23 = TAPW(2, 3), w21 = TAPW(2, 1), w22 = TAPW(2, 2), w20 = TAPW(2, 0);
    float4 w03 = TAPW(0, 3), w01 = TAPW(0, 1), w02 = TAPW(0, 2), w00 = TAPW(0, 0);
    float4 v;
    v = sd4[swz(p00, g)];      dot4(a00, v, w33);
    v = sd4[swz(p00 + 1, g)];  dot4(a00, v, w31); dot4(a01, v, w32);
    v = sd4[swz(p00 + 2, g)];  dot4(a01, v, w30);
    v = sd4[swz(p00 + 18, g)]; dot4(a00, v, w13); dot4(a10, v, w23);
    v = sd4[swz(p00 + 19, g)]; dot4(a00, v, w11); dot4(a01, v, w12); dot4(a10, v, w21); dot4(a11, v, w22);
    v = sd4[swz(p00 + 20, g)]; dot4(a01, v, w10); dot4(a11, v, w20);
    v = sd4[swz(p00 + 36, g)]; dot4(a10, v, w03);
    v = sd4[swz(p00 + 37, g)]; dot4(a10, v, w01); dot4(a11, v, w02);
    v = sd4[swz(p00 + 38, g)]; dot4(a11, v, w00);
  }
#undef TAPW

  int oy = 32 * tY + 2 * ly, ox = 32 * tX + 2 * lx;
  size_t ob = (size_t)b * 262144 + (size_t)oy * 512 + ox;
  float o0 = 1.f / (1.f + expf(-a00));
  float o1 = 1.f / (1.f + expf(-a01));
  float o2 = 1.f / (1.f + expf(-a10));
  float o3 = 1.f / (1.f + expf(-a11));
  if (m) {
    bf16* op = (bf16*)outp;
    op[ob] = __float2bfloat16(o0);       op[ob + 1] = __float2bfloat16(o1);
    op[ob + 512] = __float2bfloat16(o2); op[ob + 513] = __float2bfloat16(o3);
  } else {
    float* op = (float*)outp;
    op[ob] = o0;       op[ob + 1] = o1;
    op[ob + 512] = o2; op[ob + 513] = o3;
  }
  float d0_ = ldv(x, ob, m) - o0;
  float d1_ = ldv(x, ob + 1, m) - o1;
  float d2_ = ldv(x, ob + 512, m) - o2;
  float d3_ = ldv(x, ob + 513, m) - o3;
  float ds = fmaf(d0_, d0_, fmaf(d1_, d1_, fmaf(d2_, d2_, d3_ * d3_)));
  block_sum1(ds, rp + bx);
}

__global__ __launch_bounds__(256) void finalize_k(const double* __restrict__ vp, const double* __restrict__ rp,
                                                  void* outp, const int* modep) {
  double s = 0, rr = 0;
  for (int i = threadIdx.x; i < 512; i += 256) s += vp[i];
  for (int i = threadIdx.x; i < 8192; i += 256) rr += rp[i];
#pragma unroll
  for (int o = 32; o; o >>= 1) { s += __shfl_down(s, o, 64); rr += __shfl_down(rr, o, 64); }
  __shared__ double l1[4], l2[4];
  int lane = threadIdx.x & 63, w = threadIdx.x >> 6;
  if (lane == 0) { l1[w] = s; l2[w] = rr; }
  __syncthreads();
  if (threadIdx.x == 0) {
    double S = l1[0] + l1[1] + l1[2] + l1[3], R = l2[0] + l2[1] + l2[2] + l2[3];
    double total = R * (1.0 / 8388608.0) + 1.2 * (S * (1.0 / 262144.0));
    if (*modep) ((bf16*)outp)[8388608] = __float2bfloat16((float)total);
    else        ((float*)outp)[8388608] = (float)total;
  }
}

extern "C" void kernel_launch(void* const* d_in, const int* in_sizes, int n_in,
                              void* d_out, int out_size, void* d_ws, size_t ws_size,
                              hipStream_t stream) {
  const void* x    = d_in[0];
  const void* w1   = d_in[1];  const void* b1  = d_in[2];
  const void* g1   = d_in[3];  const void* be1 = d_in[4];
  const void* w2   = d_in[5];  const void* b2  = d_in[6];
  const void* g2   = d_in[7];  const void* be2 = d_in[8];
  const void* w3   = d_in[9];  const void* b3  = d_in[10];
  const void* g3   = d_in[11]; const void* be3 = d_in[12];
  const void* wpre = d_in[13]; const void* bpre= d_in[14];
  const void* cbk  = d_in[15];
  const void* wpost= d_in[16]; const void* bpost= d_in[17];
  const void* wd1  = d_in[18]; const void* bd1 = d_in[19];
  const void* g4   = d_in[20]; const void* be4 = d_in[21];
  const void* wd2  = d_in[22]; const void* bd2 = d_in[23];
  const void* g5   = d_in[24]; const void* be5 = d_in[25];
  const void* wd3  = d_in[26]; const void* bd3 = d_in[27];

  char* ws = (char*)d_ws;
  int*    MODE = (int*)ws;
  float*  STF  = (float*)(ws + 1024);      // 5 layers x 32 f
  double* STD  = (double*)(ws + 4096);     // 5 layers x 32 d
  float*  PF   = (float*)(ws + 8192);
  double* PD   = (double*)(ws + 73728);
  D2*     P1   = (D2*)(ws + 131072);       // 16*8192
  D2*     P2   = (D2*)(ws + 2228224);      // 16*2048
  D2*     P3   = (D2*)(ws + 2752512);      // 4*512
  D2*     P4   = (D2*)(ws + 2785280);      // 16*2048
  D2*     P5   = (D2*)(ws + 3309568);      // 16*2048
  double* VP   = (double*)(ws + 3833856);  // 512
  double* RP   = (double*)(ws + 3837952);  // 8192
  char* HB = ws + 6291456;
  float*    H1  = (float*)HB;                     // 134 MB, 4 g-planes of 32 MB
  float*    H2  = (float*)(HB + 134217728);       // 33.5 MB
  double*   C3  = (double*)HB;                    // 4 MB, reuses dead H1
  float*    D0  = (float*)(HB + 165675008);       // 2 MB, inside dead H2
  float*    D1  = (float*)HB;                     // 32 MB, 4 g-planes, reuses dead C3
  float*    D2T = (float*)(HB + 33554432);        // 134 MB f32 NHWC, overwrites dead H2/D0

  prep_k<<<1, 256, 0, stream>>>((const unsigned*)x, MODE,
                                w1, b1, w2, b2, w3, b3, wpre, bpre, cbk, wpost, bpost,
                                wd1, bd1, wd2, bd2, wd3, bd3,
                                g1, be1, g2, be2, g3, be3, g4, be4, g5, be5, PF, PD);

  conv1_t<<<8192, 256, 0, stream>>>(x, PF, H1, P1, MODE);
  bn_reduce_k<<<16, 256, 0, stream>>>(P1, 8192, STD + 0, STF + 0, PF + 9856, 1.0 / 2097152.0);

  conv2_t<<<2048, 256, 0, stream>>>(H1, PF, STF + 0, H2, P2);
  bn_reduce_k<<<16, 256, 0, stream>>>(P2, 2048, STD + 32, STF + 32, PF + 9888, 1.0 / 524288.0);

  conv3_k<<<512, 256, 0, stream>>>(H2, PD, STF + 32, C3, P3);
  bn_reduce_k<<<4, 256, 0, stream>>>(P3, 512, STD + 64, STF + 64, PF + 9920, 1.0 / 131072.0);

  vq_k<<<512, 256, 0, stream>>>(C3, PD, STD + 64, D0, VP);

  deconv1_k<<<dim3(512, 4), 256, 0, stream>>>(D0, PF, D1, P4);
  bn_reduce_k<<<16, 256, 0, stream>>>(P4, 2048, STD + 96, STF + 96, PF + 9952, 1.0 / 524288.0);

  deconv2_t<<<2048, 256, 0, stream>>>(D1, PF, STF + 96, D2T, P5);
  bn_reduce_k<<<16, 256, 0, stream>>>(P5, 2048, STD + 128, STF + 128, PF + 9984, 1.0 / 2097152.0);

  deconv3_t<<<8192, 256, 0, stream>>>(D2T, PF, STF + 128, x, d_out, RP, MODE);
  finalize_k<<<1, 256, 0, stream>>>(VP, RP, d_out, MODE);
}

// Round 9
// 534.905 us; speedup vs baseline: 1.3072x; 1.0083x over previous
//
#include <hip/hip_runtime.h>
#include <hip/hip_bf16.h>
#include <math.h>

using bf16 = __hip_bfloat16;

__device__ __forceinline__ float b2f(bf16 v) { return __bfloat162float(v); }
// mode: 1 = inputs bf16, 0 = inputs f32
__device__ __forceinline__ float ldv(const void* p, size_t i, int m) {
  return m ? b2f(((const bf16*)p)[i]) : ((const float*)p)[i];
}

struct D2 { double s, s2; };

// ---- block reductions (blockDim == 256), non-atomic partial writes ----
__device__ __forceinline__ void block_stats1(float v, D2* slot) {
  float v2 = v * v;
#pragma unroll
  for (int o = 32; o; o >>= 1) { v += __shfl_down(v, o, 64); v2 += __shfl_down(v2, o, 64); }
  __shared__ float a1[4], a2[4];
  int lane = threadIdx.x & 63, w = threadIdx.x >> 6;
  if (lane == 0) { a1[w] = v; a2[w] = v2; }
  __syncthreads();
  if (threadIdx.x == 0) {
    slot->s  = (double)a1[0] + a1[1] + a1[2] + a1[3];
    slot->s2 = (double)a2[0] + a2[1] + a2[2] + a2[3];
  }
}

// 4 doubles at once (single barrier, no cross-call race)
__device__ __forceinline__ void block_stats1d4(const double* v, const double* vq, D2* base, int NB, int bx) {
  __shared__ double q1[16], q2[16];
  int lane = threadIdx.x & 63, w = threadIdx.x >> 6;
#pragma unroll
  for (int k = 0; k < 4; k++) {
    double s = v[k], s2 = vq[k];
#pragma unroll
    for (int o = 32; o; o >>= 1) { s += __shfl_down(s, o, 64); s2 += __shfl_down(s2, o, 64); }
    if (lane == 0) { q1[k * 4 + w] = s; q2[k * 4 + w] = s2; }
  }
  __syncthreads();
  if (threadIdx.x < 4) {
    int k = threadIdx.x;
    base[k * NB + bx].s  = q1[k * 4] + q1[k * 4 + 1] + q1[k * 4 + 2] + q1[k * 4 + 3];
    base[k * NB + bx].s2 = q2[k * 4] + q2[k * 4 + 1] + q2[k * 4 + 2] + q2[k * 4 + 3];
  }
}

__device__ __forceinline__ void block_sum1(float v, double* slot) {
#pragma unroll
  for (int o = 32; o; o >>= 1) v += __shfl_down(v, o, 64);
  __shared__ float a1[4];
  int lane = threadIdx.x & 63, w = threadIdx.x >> 6;
  if (lane == 0) a1[w] = v;
  __syncthreads();
  if (threadIdx.x == 0) *slot = (double)a1[0] + a1[1] + a1[2] + a1[3];
}

// 16-channel block stats -> part[co*NB + bx]
__device__ __forceinline__ void block_stats16(const float* vs, const float* vq, D2* base, int NB, int bx) {
  __shared__ float s1[64], s2[64];
  int lane = threadIdx.x & 63, w = threadIdx.x >> 6;
#pragma unroll
  for (int co = 0; co < 16; co++) {
    float v = vs[co], v2 = vq[co];
#pragma unroll
    for (int o = 32; o; o >>= 1) { v += __shfl_down(v, o, 64); v2 += __shfl_down(v2, o, 64); }
    if (lane == 0) { s1[co * 4 + w] = v; s2[co * 4 + w] = v2; }
  }
  __syncthreads();
  if (threadIdx.x < 16) {
    int co = threadIdx.x;
    base[co * NB + bx].s  = (double)s1[co * 4] + s1[co * 4 + 1] + s1[co * 4 + 2] + s1[co * 4 + 3];
    base[co * NB + bx].s2 = (double)s2[co * 4] + s2[co * 4 + 1] + s2[co * 4 + 2] + s2[co * 4 + 3];
  }
}

// PF float layout: W1 0(256) B1 256(16)
//   W2N 272(4096,[cig*1024+tap*64+c4*16+co])  <- conv2 pass-major layout
//   B2 4368(16)
//   WD1 4384(1024, legacy) BD1 5408(16) WD2 5424(4096, legacy)
//   BD2 9520(16) WD3 9536(256, legacy) BD3 9792(1) G/BE 9856+l*32 (gamma 16, beta 16)
//   WD3T 10016(256,[tap*16+ci])   <- tap-major copy for deconv3
//   WD2T 10272(4096,[ci*256+tap*16+co]) <- co-contiguous per (ci,tap) for deconv2
//   WD1T 14368(1024,[ci*256+tap*16+co]) <- co-contiguous per (ci,tap) for deconv1
// PD double layout: W3 0(1024,[co*256+ci*16+tap]) B3 1024(4) WPRE 1028(8) BPRE 1036(2)
//   CB 1040(512) WPOST 1552(8) BPOST 1560(4)
__global__ void prep_k(const unsigned* __restrict__ xw, int* __restrict__ MODE,
                       const void* w1, const void* b1, const void* w2, const void* b2,
                       const void* w3, const void* b3, const void* wpre, const void* bpre,
                       const void* cbk, const void* wpost, const void* bpost,
                       const void* wd1, const void* bd1, const void* wd2, const void* bd2,
                       const void* wd3, const void* bd3,
                       const void* g1, const void* be1, const void* g2, const void* be2,
                       const void* g3, const void* be3, const void* g4, const void* be4,
                       const void* g5, const void* be5,
                       float* __restrict__ PF, double* __restrict__ PD) {
  int t = threadIdx.x;
  // ---- dtype detect (merged init) ----
  __shared__ int smode;
  {
    unsigned lo = xw[t] & 0xFFFFu;
    int inr = (lo >= 0x3000u && lo < 0x4000u) ? 1 : 0;
    unsigned long long b = __ballot(inr);
    __shared__ int cnt[4];
    if ((t & 63) == 0) cnt[t >> 6] = __popcll(b);
    __syncthreads();
    if (t == 0) { smode = (cnt[0] + cnt[1] + cnt[2] + cnt[3] >= 128) ? 1 : 0; *MODE = smode; }
    __syncthreads();
  }
  int m = smode;
  for (int i = t; i < 256; i += 256) PF[i] = ldv(w1, i, m);
  if (t < 16) PF[256 + t] = ldv(b1, t, m);
  for (int i = t; i < 4096; i += 256) {   // w2 (16,16,4,4) -> [cig*1024+tap*64+c4*16+co]
    int cig = i >> 10, tap = (i >> 6) & 15, c4 = (i >> 4) & 3, co = i & 15;
    PF[272 + i] = ldv(w2, co * 256 + (cig * 4 + c4) * 16 + tap, m);
  }
  if (t < 16) PF[4368 + t] = ldv(b2, t, m);
  for (int i = t; i < 1024; i += 256) {   // wd1 (4,16,4,4) -> [co*64+ci*16+tap] (legacy)
    int co = i >> 6, ci = (i >> 4) & 3, tap = i & 15;
    PF[4384 + i] = ldv(wd1, ci * 256 + co * 16 + tap, m);
  }
  for (int i = t; i < 1024; i += 256) {   // wd1 -> [ci*256+tap*16+co]
    int ci = i >> 8, tap = (i >> 4) & 15, co = i & 15;
    PF[14368 + i] = ldv(wd1, ci * 256 + co * 16 + tap, m);
  }
  if (t < 16) PF[5408 + t] = ldv(bd1, t, m);
  for (int i = t; i < 4096; i += 256) {   // wd2 legacy
    int co = i >> 8, ci = (i >> 4) & 15, tap = i & 15;
    PF[5424 + i] = ldv(wd2, ci * 256 + co * 16 + tap, m);
  }
  for (int i = t; i < 4096; i += 256) {   // wd2 -> [ci*256+tap*16+co]
    int ci = i >> 8, tap = (i >> 4) & 15, co = i & 15;
    PF[10272 + i] = ldv(wd2, ci * 256 + co * 16 + tap, m);
  }
  if (t < 16) PF[9520 + t] = ldv(bd2, t, m);
  for (int i = t; i < 256; i += 256) PF[9536 + i] = ldv(wd3, i, m);
  {   // tap-major wd3: WT[tap*16 + ci] = wd3[ci*16 + tap]
    int tap = t >> 4, ci = t & 15;
    PF[10016 + t] = ldv(wd3, ci * 16 + tap, m);
  }
  if (t == 0) PF[9792] = ldv(bd3, 0, m);
  if (t < 16) {
    PF[9856 + t] = ldv(g1, t, m);  PF[9872 + t] = ldv(be1, t, m);
    PF[9888 + t] = ldv(g2, t, m);  PF[9904 + t] = ldv(be2, t, m);
    PF[9952 + t] = ldv(g4, t, m);  PF[9968 + t] = ldv(be4, t, m);
    PF[9984 + t] = ldv(g5, t, m);  PF[10000 + t] = ldv(be5, t, m);
  }
  if (t < 4) { PF[9920 + t] = ldv(g3, t, m); PF[9936 + t] = ldv(be3, t, m); }
  for (int i = t; i < 1024; i += 256) PD[i] = ldv(w3, i, m);
  if (t < 4) PD[1024 + t] = ldv(b3, t, m);
  if (t < 8) PD[1028 + t] = ldv(wpre, t, m);
  if (t < 2) PD[1036 + t] = ldv(bpre, t, m);
  for (int i = t; i < 512; i += 256) PD[1040 + i] = ldv(cbk, i, m);
  if (t < 8) PD[1552 + t] = ldv(wpost, t, m);
  if (t < 4) PD[1560 + t] = ldv(bpost, t, m);
}

// ---- BN reduce: partials -> scale/shift (f64 + f32) ----
__global__ __launch_bounds__(256) void bn_reduce_k(const D2* __restrict__ part, int NB,
                                                   double* __restrict__ stD, float* __restrict__ stF,
                                                   const float* __restrict__ gb, double invN) {
  int c = blockIdx.x;
  double s = 0, s2 = 0;
  for (int i = threadIdx.x; i < NB; i += 256) { D2 p = part[c * NB + i]; s += p.s; s2 += p.s2; }
#pragma unroll
  for (int o = 32; o; o >>= 1) { s += __shfl_down(s, o, 64); s2 += __shfl_down(s2, o, 64); }
  __shared__ double l1[4], l2[4];
  int lane = threadIdx.x & 63, w = threadIdx.x >> 6;
  if (lane == 0) { l1[w] = s; l2[w] = s2; }
  __syncthreads();
  if (threadIdx.x == 0) {
    double S = l1[0] + l1[1] + l1[2] + l1[3], Q = l2[0] + l2[1] + l2[2] + l2[3];
    double mu = S * invN, var = Q * invN - mu * mu;
    if (var < 0) var = 0;
    double sc = (double)gb[c] / sqrt(var + 1e-5);
    double sh = (double)gb[16 + c] - mu * sc;
    stD[c] = sc; stD[16 + c] = sh;
    stF[c] = (float)sc; stF[16 + c] = (float)sh;
  }
}

// ---- conv1 tiled: 64x4 tile, all 16 co per block, x staged once in LDS ----
// Output H1 is channel-group planar: plane g (g=co>>2) is [b][y][x][4],
// plane stride 8388608 floats (32 MB). Pixel index pix=(b*65536+oy*256+ox).
__global__ __launch_bounds__(256) void conv1_t(const void* __restrict__ x, const float* __restrict__ PF,
                                               float* __restrict__ y, D2* __restrict__ part,
                                               const int* modep) {
  const int m = *modep;
  __shared__ float sx[10 * 130];
  int t = threadIdx.x;
  int bx = blockIdx.x;
  int b = bx >> 8, r = bx & 255, tY = r >> 2, tX = r & 3;   // 64 tY x 4 tX tiles of 64x4
  int iy0 = 8 * tY - 1, ix0 = 128 * tX - 1;
  size_t xb = (size_t)b * 262144;
  for (int i = t; i < 1300; i += 256) {
    int ry = i / 130, rx = i - ry * 130;
    int gy = iy0 + ry, gx = ix0 + rx;
    float v = 0.f;
    if ((unsigned)gy < 512u && (unsigned)gx < 512u) v = ldv(x, xb + (size_t)gy * 512 + gx, m);
    sx[i] = v;
  }
  __syncthreads();
  int tyy = t >> 6, txx = t & 63;
  int oy = tY * 4 + tyy, ox = tX * 64 + txx;
  float acc[16];
#pragma unroll
  for (int co = 0; co < 16; co++) acc[co] = PF[256 + co];
  int ly = 2 * tyy, lx = 2 * txx;
#pragma unroll
  for (int ky = 0; ky < 4; ky++) {
#pragma unroll
    for (int kx = 0; kx < 4; kx++) {
      float v = sx[(ly + ky) * 130 + lx + kx];
#pragma unroll
      for (int co = 0; co < 16; co++) acc[co] = fmaf(v, PF[co * 16 + ky * 4 + kx], acc[co]);
    }
  }
  size_t pix = (size_t)b * 65536 + (size_t)(oy * 256 + ox);
  *(float4*)(y + 0 * 8388608 + pix * 4) = make_float4(acc[0],  acc[1],  acc[2],  acc[3]);
  *(float4*)(y + 1 * 8388608 + pix * 4) = make_float4(acc[4],  acc[5],  acc[6],  acc[7]);
  *(float4*)(y + 2 * 8388608 + pix * 4) = make_float4(acc[8],  acc[9],  acc[10], acc[11]);
  *(float4*)(y + 3 * 8388608 + pix * 4) = make_float4(acc[12], acc[13], acc[14], acc[15]);
  float vq_[16];
#pragma unroll
  for (int co = 0; co < 16; co++) vq_[co] = acc[co] * acc[co];
  block_stats16(acc, vq_, part, 8192, bx);
}

// ---- conv2: g-planar input, 4 passes of 4 ci each, async-stage prefetch.
// ---- LDS is plane-interleaved float4 [q][34][18]: one ds_write_b128 per
// ---- staged pixel, one ds_read_b128 per tap (was 4x scalar each).
__device__ __forceinline__ float4 aff_relu4(float4 v, float4 sc, float4 sh) {
  v.x = fmaxf(fmaf(v.x, sc.x, sh.x), 0.f);
  v.y = fmaxf(fmaf(v.y, sc.y, sh.y), 0.f);
  v.z = fmaxf(fmaf(v.z, sc.z, sh.z), 0.f);
  v.w = fmaxf(fmaf(v.w, sc.w, sh.w), 0.f);
  return v;
}

__global__ __launch_bounds__(256, 6) void conv2_t(const float* __restrict__ h1, const float* __restrict__ PF,
                                                  const float* __restrict__ aff, float* __restrict__ h2,
                                                  D2* __restrict__ part) {
  __shared__ float4 su4[1224];   // [q=2][34][18] x float4(4 planes) = 19584 B
  int t = threadIdx.x, ty = t >> 4, tx = t & 15;
  int bx = blockIdx.x, bb = bx >> 6, r = bx & 63, tY = r >> 3, tX = r & 7;
  int oy = tY * 16 + ty, ox = tX * 16 + tx;
  int iy0 = 32 * tY - 1, ix0 = 32 * tX - 1;
  const float* W2 = PF + 272;              // [cig*1024 + tap*64 + c4*16 + co]
  const float4* A4 = (const float4*)aff;
  // precompute staging geometry (same for all g)
  int goff[5], soff[5];
#pragma unroll
  for (int k = 0; k < 5; k++) {
    int i = t + k * 256;
    goff[k] = -1; soff[k] = -1;
    if (i < 1156) {
      int riy = i / 34, rix = i - riy * 34;
      int gy = iy0 + riy, gx = ix0 + rix;
      soff[k] = (rix & 1) * 612 + riy * 18 + (rix >> 1);
      if ((unsigned)gy < 256u && (unsigned)gx < 256u) goff[k] = (gy * 256 + gx) * 4;
    }
  }
  const float* pb = h1 + (size_t)bb * 262144;
  float4 rv[5];
#pragma unroll
  for (int k = 0; k < 5; k++) {
    float4 v = make_float4(0.f, 0.f, 0.f, 0.f);
    if (goff[k] >= 0) v = *(const float4*)(pb + goff[k]);
    rv[k] = v;
  }
  float acc[16];
#pragma unroll
  for (int co = 0; co < 16; co++) acc[co] = PF[4368 + co];
#pragma unroll
  for (int g = 0; g < 4; g++) {
    float4 SC = A4[g], SH = A4[4 + g];
    __syncthreads();
#pragma unroll
    for (int k = 0; k < 5; k++) {
      if (soff[k] >= 0) {
        float4 v = make_float4(0.f, 0.f, 0.f, 0.f);
        if (goff[k] >= 0) v = aff_relu4(rv[k], SC, SH);   // affine ONLY in-bounds; pad stays 0
        su4[soff[k]] = v;
      }
    }
    __syncthreads();
    if (g < 3) {
      const float* pg = pb + (size_t)(g + 1) * 8388608;
#pragma unroll
      for (int k = 0; k < 5; k++) {
        float4 v = make_float4(0.f, 0.f, 0.f, 0.f);
        if (goff[k] >= 0) v = *(const float4*)(pg + goff[k]);
        rv[k] = v;
      }
    }
    const float* wg = W2 + g * 1024;
    int base = 2 * ty * 18 + tx;
#pragma unroll
    for (int ky = 0; ky < 4; ky++) {
#pragma unroll
      for (int kx = 0; kx < 4; kx++) {
        float4 vv = su4[(kx & 1) * 612 + ky * 18 + (kx >> 1) + base];
        const float* wt = wg + (ky * 4 + kx) * 64;
#pragma unroll
        for (int co = 0; co < 16; co++) {
          float s0 = fmaf(vv.x, wt[co], acc[co]);
          float s1 = fmaf(vv.y, wt[16 + co], s0);
          float s2 = fmaf(vv.z, wt[32 + co], s1);
          acc[co] = fmaf(vv.w, wt[48 + co], s2);
        }
      }
    }
  }
  float vq_[16];
#pragma unroll
  for (int co = 0; co < 16; co++) {
    h2[((size_t)(bb * 16 + co) * 128 + oy) * 128 + ox] = acc[co];
    vq_[co] = acc[co] * acc[co];
  }
  block_stats16(acc, vq_, part, 2048, bx);
}

// ---- conv3: all 4 co per thread; f32 h2 (affine2+relu) -> f64 raw (32,4,64,64) ----
__global__ __launch_bounds__(256) void conv3_k(const float* __restrict__ h2, const double* __restrict__ PD,
                                               const float* __restrict__ aff, double* __restrict__ c3,
                                               D2* __restrict__ part) {
  int idx = blockIdx.x * 256 + threadIdx.x;   // 131072
  int b = idx >> 12, rem = idx & 4095, oy = rem >> 6, ox = rem & 63;
  double a0 = PD[1024], a1 = PD[1025], a2 = PD[1026], a3 = PD[1027];
  int iy0 = 2 * oy - 1, ix0 = 2 * ox - 1;
  for (int ci = 0; ci < 16; ci++) {
    const float* ib = h2 + (size_t)(b * 16 + ci) * 16384;
    float sc = aff[ci], sh = aff[16 + ci];
    const double* wr = PD + ci * 16;   // + co*256 per output
#pragma unroll
    for (int ky = 0; ky < 4; ky++) {
      int iy = iy0 + ky;
      if ((unsigned)iy < 128u) {
        const float* row = ib + iy * 128;
#pragma unroll
        for (int kx = 0; kx < 4; kx++) {
          int ix = ix0 + kx;
          if ((unsigned)ix < 128u) {
            double v = (double)fmaxf(fmaf(row[ix], sc, sh), 0.f);
            int tp = ky * 4 + kx;
            a0 = fma(v, wr[tp], a0);
            a1 = fma(v, wr[256 + tp], a1);
            a2 = fma(v, wr[512 + tp], a2);
            a3 = fma(v, wr[768 + tp], a3);
          }
        }
      }
    }
  }
  size_t cb = (size_t)b * 16384 + rem;
  c3[cb] = a0; c3[cb + 4096] = a1; c3[cb + 8192] = a2; c3[cb + 12288] = a3;
  double vs[4] = {a0, a1, a2, a3};
  double vq[4] = {a0 * a0, a1 * a1, a2 * a2, a3 * a3};
  block_stats1d4(vs, vq, part, 512, blockIdx.x);
}

// ---- VQ: f64 BN3 affine+relu -> wpre -> argmin -> wpost -> d0 (f32) ----
__global__ __launch_bounds__(256) void vq_k(const double* __restrict__ c3, const double* __restrict__ PD,
                                            const double* __restrict__ stD2, float* __restrict__ d0,
                                            double* __restrict__ vp) {
  __shared__ double cb[512];
  for (int i = threadIdx.x; i < 512; i += 256) cb[i] = PD[1040 + i];
  __syncthreads();
  int pix = blockIdx.x * 256 + threadIdx.x;
  int b = pix >> 12, rem = pix & 4095;
  const double* hb = c3 + (size_t)b * 16384 + rem;
  double q0 = PD[1036], q1 = PD[1037];
#pragma unroll
  for (int ci = 0; ci < 4; ci++) {
    double v = fma(hb[ci * 4096], stD2[ci], stD2[16 + ci]);
    if (v < 0) v = 0;
    q0 = fma(v, PD[1028 + ci], q0);
    q1 = fma(v, PD[1032 + ci], q1);
  }
  int best = 0;
  double bd = 1e300;
  for (int k = 0; k < 256; k++) {
    double dx = q0 - cb[2 * k], dy = q1 - cb[2 * k + 1];
    double d = dx * dx + dy * dy;
    if (d < bd) { bd = d; best = k; }   // strict < == first-index argmin
  }
  double c0 = cb[2 * best], c1 = cb[2 * best + 1];
  double e0 = q0 - c0, e1 = q1 - c1;
  float* ob = d0 + (size_t)b * 16384 + rem;
#pragma unroll
  for (int c = 0; c < 4; c++)
    ob[c * 4096] = (float)(PD[1560 + c] + PD[1552 + 2 * c] * c0 + PD[1552 + 2 * c + 1] * c1);
  double v = e0 * e0 + e1 * e1;
#pragma unroll
  for (int o = 32; o; o >>= 1) v += __shfl_down(v, o, 64);
  __shared__ double l1[4];
  int lane = threadIdx.x & 63, w = threadIdx.x >> 6;
  if (lane == 0) l1[w] = v;
  __syncthreads();
  if (threadIdx.x == 0) vp[blockIdx.x] = l1[0] + l1[1] + l1[2] + l1[3];
}

// ---- deconv1: parity-phase grid (512, phase). d1 g-planar f32. ----
__global__ __launch_bounds__(256) void deconv1_k(const float* __restrict__ d0, const float* __restrict__ PF,
                                                 float* __restrict__ d1, D2* __restrict__ part) {
  int phase = blockIdx.y, a = phase >> 1, bc = phase & 1;
  int idx = blockIdx.x * 256 + threadIdx.x;   // 131072 quads
  int b = idx >> 12, rem = idx & 4095, qy = rem >> 6, qx = rem & 63;
  const float* WT = PF + 14368;   // [ci*256 + tap*16 + co]
  float acc[16];
#pragma unroll
  for (int co = 0; co < 16; co++) acc[co] = PF[5408 + co];
  const float* hb = d0 + (size_t)b * 16384;
#pragma unroll
  for (int t2y = 0; t2y < 2; t2y++) {
    int iy = qy + a - t2y;
    if ((unsigned)iy < 64u) {
      int kyo = (1 - a + 2 * t2y) * 4;
#pragma unroll
      for (int t2x = 0; t2x < 2; t2x++) {
        int ix = qx + bc - t2x;
        if ((unsigned)ix < 64u) {
          int tap = kyo + (1 - bc + 2 * t2x);
          int off = iy * 64 + ix;
#pragma unroll
          for (int ci = 0; ci < 4; ci++) {
            float v = hb[ci * 4096 + off];
            const float* wt = WT + ci * 256 + tap * 16;
#pragma unroll
            for (int co = 0; co < 16; co++) acc[co] = fmaf(v, wt[co], acc[co]);
          }
        }
      }
    }
  }
  int oy = 2 * qy + a, ox = 2 * qx + bc;
  size_t pix = (size_t)b * 16384 + (size_t)(oy * 128 + ox);
  *(float4*)(d1 + 0 * 2097152 + pix * 4) = make_float4(acc[0],  acc[1],  acc[2],  acc[3]);
  *(float4*)(d1 + 1 * 2097152 + pix * 4) = make_float4(acc[4],  acc[5],  acc[6],  acc[7]);
  *(float4*)(d1 + 2 * 2097152 + pix * 4) = make_float4(acc[8],  acc[9],  acc[10], acc[11]);
  *(float4*)(d1 + 3 * 2097152 + pix * 4) = make_float4(acc[12], acc[13], acc[14], acc[15]);
  float vq_[16];
#pragma unroll
  for (int co = 0; co < 16; co++) vq_[co] = acc[co] * acc[co];
  block_stats16(acc, vq_, part, 2048, blockIdx.y * 512 + blockIdx.x);
}

// ---- deconv2: parity-phase compute, g-planar float4 staging, f32 NHWC out ----
// ---- Output NHWC: d2[((b*65536 + oy*256 + ox)*16) + co]
__global__ __launch_bounds__(256) void deconv2_t(const float* __restrict__ d1, const float* __restrict__ PF,
                                                 const float* __restrict__ aff, float* __restrict__ d2,
                                                 D2* __restrict__ part) {
  __shared__ float su[16 * 324];
  int t = threadIdx.x, py = t >> 4, px = t & 15;
  int bx = blockIdx.x, bb = bx >> 6, r = bx & 63, tY = r >> 3, tX = r & 7;
  int iy0 = 16 * tY - 1, ix0 = 16 * tX - 1;
  const float4* A4 = (const float4*)aff;
  for (int i = t; i < 1296; i += 256) {
    int g = i / 324, rr = i - g * 324;
    int riy = rr / 18, rix = rr - riy * 18;
    int gy = iy0 + riy, gx = ix0 + rix;
    float4 v = make_float4(0.f, 0.f, 0.f, 0.f);
    if ((unsigned)gy < 128u && (unsigned)gx < 128u)
      v = aff_relu4(*(const float4*)(d1 + (size_t)g * 2097152 +
                                     ((size_t)bb * 16384 + (size_t)(gy * 128 + gx)) * 4),
                    A4[g], A4[4 + g]);
    int s0 = g * 1296 + rr;   // su[(g*4+c4)*324 + rr]
    su[s0] = v.x; su[s0 + 324] = v.y; su[s0 + 648] = v.z; su[s0 + 972] = v.w;
  }
  __syncthreads();
  const float* WT = PF + 10272;   // [ci*256 + tap*16 + co]
  float vs[16], vq[16];
#pragma unroll
  for (int co = 0; co < 16; co++) { vs[co] = 0.f; vq[co] = 0.f; }
#pragma unroll
  for (int a = 0; a < 2; a++) {
#pragma unroll
    for (int bc = 0; bc < 2; bc++) {
      float acc[16];
#pragma unroll
      for (int co = 0; co < 16; co++) acc[co] = PF[9520 + co];
      int base = (py + a) * 18 + (px + bc);
      for (int ci = 0; ci < 16; ci++) {
        const float* sb = su + ci * 324 + base;
        float v00 = sb[0], v01 = sb[1], v10 = sb[18], v11 = sb[19];
        const float* wci = WT + ci * 256;
        const float* w00p = wci + (((3 - a) * 4 + (3 - bc)) << 4);
        const float* w01p = wci + (((3 - a) * 4 + (1 - bc)) << 4);
        const float* w10p = wci + (((1 - a) * 4 + (3 - bc)) << 4);
        const float* w11p = wci + (((1 - a) * 4 + (1 - bc)) << 4);
#pragma unroll
        for (int co = 0; co < 16; co++) {
          float s0 = fmaf(v00, w00p[co], acc[co]);
          float s1 = fmaf(v01, w01p[co], s0);
          float s2 = fmaf(v10, w10p[co], s1);
          acc[co] = fmaf(v11, w11p[co], s2);
        }
      }
      int oy = 32 * tY + 2 * py + a, ox = 32 * tX + 2 * px + bc;
      float4* dst = (float4*)(d2 + ((size_t)bb * 65536 + (size_t)oy * 256 + ox) * 16);
      dst[0] = make_float4(acc[0],  acc[1],  acc[2],  acc[3]);
      dst[1] = make_float4(acc[4],  acc[5],  acc[6],  acc[7]);
      dst[2] = make_float4(acc[8],  acc[9],  acc[10], acc[11]);
      dst[3] = make_float4(acc[12], acc[13], acc[14], acc[15]);
#pragma unroll
      for (int co = 0; co < 16; co++) {
        vs[co] += acc[co];
        vq[co] = fmaf(acc[co], acc[co], vq[co]);
      }
    }
  }
  block_stats16(vs, vq, part, 2048, bx);
}

// ---- deconv3: f32 NHWC d2, 16x16 input tile -> 32x32 output tile ----
__device__ __forceinline__ int swz(int p, int g) {
  int s = p * 4 + (g ^ (p & 3));       // rotate channel-group by pixel&3
  return s ^ (((p >> 2) & 1) << 2);    // XOR slot bit2 with slot bit4 (involution)
}

__device__ __forceinline__ float4 aff_relu(float4 v, float4 sc, float4 sh) {
  v.x = fmaxf(fmaf(v.x, sc.x, sh.x), 0.f);
  v.y = fmaxf(fmaf(v.y, sc.y, sh.y), 0.f);
  v.z = fmaxf(fmaf(v.z, sc.z, sh.z), 0.f);
  v.w = fmaxf(fmaf(v.w, sc.w, sh.w), 0.f);
  return v;
}

__device__ __forceinline__ void dot4(float& a, float4 v, float4 w) {
  a = fmaf(v.x, w.x, a); a = fmaf(v.y, w.y, a);
  a = fmaf(v.z, w.z, a); a = fmaf(v.w, w.w, a);
}

__global__ __launch_bounds__(256, 4) void deconv3_t(const float* __restrict__ d2, const float* __restrict__ PF,
                                                    const float* __restrict__ aff, const void* __restrict__ x,
                                                    void* __restrict__ outp, double* __restrict__ rp,
                                                    const int* __restrict__ modep) {
  const int m = *modep;
  __shared__ float4 sd4[1296];          // 18*18 pixels * 4 channel-groups, swizzled
  int t = threadIdx.x;
  int bx = blockIdx.x;
  int b = bx >> 8, r = bx & 255, tY = r >> 4, tX = r & 15;   // 16x16 tiles of 16x16 input px
  int iy0 = 16 * tY - 1, ix0 = 16 * tX - 1;
  const float4* A4 = (const float4*)aff;
  float4 SC0 = A4[0], SC1 = A4[1], SC2 = A4[2], SC3 = A4[3];
  float4 SH0 = A4[4], SH1 = A4[5], SH2 = A4[6], SH3 = A4[7];
  const float* db = d2 + (size_t)b * 1048576;   // NHWC, 256*256*16 per batch
  for (int p = t; p < 324; p += 256) {
    int riy = p / 18, rix = p - riy * 18;
    int gy = iy0 + riy, gx = ix0 + rix;
    float4 v0, v1, v2, v3;
    if ((unsigned)gy < 256u && (unsigned)gx < 256u) {
      const float4* s = (const float4*)(db + ((size_t)gy * 256 + gx) * 16);
      v0 = aff_relu(s[0], SC0, SH0);
      v1 = aff_relu(s[1], SC1, SH1);
      v2 = aff_relu(s[2], SC2, SH2);
      v3 = aff_relu(s[3], SC3, SH3);
    } else {
      v0 = v1 = v2 = v3 = make_float4(0.f, 0.f, 0.f, 0.f);
    }
    sd4[swz(p, 0)] = v0; sd4[swz(p, 1)] = v1; sd4[swz(p, 2)] = v2; sd4[swz(p, 3)] = v3;
  }
  __syncthreads();

  int lx = t & 15, ly = t >> 4;          // this thread's input pixel within tile
  float bias = PF[9792];
  float a00 = bias, a01 = bias, a10 = bias, a11 = bias;
  const float* WT = PF + 10016;          // [tap*16 + ci], tap = ky*4+kx
  int p00 = ly * 18 + lx;                // LDS pixel index of (dy=-1,dx=-1)
#define TAPW(ky, kx) (*(const float4*)(WT + ((ky) * 4 + (kx)) * 16 + (g << 2)))
#pragma unroll
  for (int g = 0; g < 4; g++) {
    float4 w33 = TAPW(3, 3), w31 = TAPW(3, 1), w32 = TAPW(3, 2), w30 = TAPW(3, 0);
    float4 w13 = TAPW(1, 3), w11 = TAPW(1, 1), w12 = TAPW(1, 2), w10 = TAPW(1, 0);
    float4 w23 = TAPW(2, 3), w21 = TAPW(2, 1), w22 = TAPW(2, 2), w20 = TAPW(2, 0);
    float4 w03 = TAPW(0, 3), w01 = TAPW(0, 1), w02 = TAPW(0, 2), w00 = TAPW(0, 0);
    float4 v;
    v = sd4[swz(p00, g)];      dot4(a00, v, w33);
    v = sd4[swz(p00 + 1, g)];  dot4(a00, v, w31); dot4(a01, v, w32);
    v = sd4[swz(p00 + 2, g)];  dot4(a01, v, w30);
    v = sd4[swz(p00 + 18, g)]; dot4(a00, v, w13); dot4(a10, v, w23);
    v = sd4[swz(p00 + 19, g)]; dot4(a00, v, w11); dot4(a01, v, w12); dot4(a10, v, w21); dot4(a11, v, w22);
    v = sd4[swz(p00 + 20, g)]; dot4(a01, v, w10); dot4(a11, v, w20);
    v = sd4[swz(p00 + 36, g)]; dot4(a10, v, w03);
    v = sd4[swz(p00 + 37, g)]; dot4(a10, v, w01); dot4(a11, v, w02);
    v = sd4[swz(p00 + 38, g)]; dot4(a11, v, w00);
  }
#undef TAPW

  int oy = 32 * tY + 2 * ly, ox = 32 * tX + 2 * lx;
  size_t ob = (size_t)b * 262144 + (size_t)oy * 512 + ox;
  float o0 = 1.f / (1.f + expf(-a00));
  float o1 = 1.f / (1.f + expf(-a01));
  float o2 = 1.f / (1.f + expf(-a10));
  float o3 = 1.f / (1.f + expf(-a11));
  if (m) {
    bf16* op = (bf16*)outp;
    op[ob] = __float2bfloat16(o0);       op[ob + 1] = __float2bfloat16(o1);
    op[ob + 512] = __float2bfloat16(o2); op[ob + 513] = __float2bfloat16(o3);
  } else {
    float* op = (float*)outp;
    op[ob] = o0;       op[ob + 1] = o1;
    op[ob + 512] = o2; op[ob + 513] = o3;
  }
  float d0_ = ldv(x, ob, m) - o0;
  float d1_ = ldv(x, ob + 1, m) - o1;
  float d2_ = ldv(x, ob + 512, m) - o2;
  float d3_ = ldv(x, ob + 513, m) - o3;
  float ds = fmaf(d0_, d0_, fmaf(d1_, d1_, fmaf(d2_, d2_, d3_ * d3_)));
  block_sum1(ds, rp + bx);
}

__global__ __launch_bounds__(256) void finalize_k(const double* __restrict__ vp, const double* __restrict__ rp,
                                                  void* outp, const int* modep) {
  double s = 0, rr = 0;
  for (int i = threadIdx.x; i < 512; i += 256) s += vp[i];
  for (int i = threadIdx.x; i < 8192; i += 256) rr += rp[i];
#pragma unroll
  for (int o = 32; o; o >>= 1) { s += __shfl_down(s, o, 64); rr += __shfl_down(rr, o, 64); }
  __shared__ double l1[4], l2[4];
  int lane = threadIdx.x & 63, w = threadIdx.x >> 6;
  if (lane == 0) { l1[w] = s; l2[w] = rr; }
  __syncthreads();
  if (threadIdx.x == 0) {
    double S = l1[0] + l1[1] + l1[2] + l1[3], R = l2[0] + l2[1] + l2[2] + l2[3];
    double total = R * (1.0 / 8388608.0) + 1.2 * (S * (1.0 / 262144.0));
    if (*modep) ((bf16*)outp)[8388608] = __float2bfloat16((float)total);
    else        ((float*)outp)[8388608] = (float)total;
  }
}

extern "C" void kernel_launch(void* const* d_in, const int* in_sizes, int n_in,
                              void* d_out, int out_size, void* d_ws, size_t ws_size,
                              hipStream_t stream) {
  const void* x    = d_in[0];
  const void* w1   = d_in[1];  const void* b1  = d_in[2];
  const void* g1   = d_in[3];  const void* be1 = d_in[4];
  const void* w2   = d_in[5];  const void* b2  = d_in[6];
  const void* g2   = d_in[7];  const void* be2 = d_in[8];
  const void* w3   = d_in[9];  const void* b3  = d_in[10];
  const void* g3   = d_in[11]; const void* be3 = d_in[12];
  const void* wpre = d_in[13]; const void* bpre= d_in[14];
  const void* cbk  = d_in[15];
  const void* wpost= d_in[16]; const void* bpost= d_in[17];
  const void* wd1  = d_in[18]; const void* bd1 = d_in[19];
  const void* g4   = d_in[20]; const void* be4 = d_in[21];
  const void* wd2  = d_in[22]; const void* bd2 = d_in[23];
  const void* g5   = d_in[24]; const void* be5 = d_in[25];
  const void* wd3  = d_in[26]; const void* bd3 = d_in[27];

  char* ws = (char*)d_ws;
  int*    MODE = (int*)ws;
  float*  STF  = (float*)(ws + 1024);      // 5 layers x 32 f
  double* STD  = (double*)(ws + 4096);     // 5 layers x 32 d
  float*  PF   = (float*)(ws + 8192);
  double* PD   = (double*)(ws + 73728);
  D2*     P1   = (D2*)(ws + 131072);       // 16*8192
  D2*     P2   = (D2*)(ws + 2228224);      // 16*2048
  D2*     P3   = (D2*)(ws + 2752512);      // 4*512
  D2*     P4   = (D2*)(ws + 2785280);      // 16*2048
  D2*     P5   = (D2*)(ws + 3309568);      // 16*2048
  double* VP   = (double*)(ws + 3833856);  // 512
  double* RP   = (double*)(ws + 3837952);  // 8192
  char* HB = ws + 6291456;
  float*    H1  = (float*)HB;                     // 134 MB, 4 g-planes of 32 MB
  float*    H2  = (float*)(HB + 134217728);       // 33.5 MB
  double*   C3  = (double*)HB;                    // 4 MB, reuses dead H1
  float*    D0  = (float*)(HB + 165675008);       // 2 MB, inside dead H2
  float*    D1  = (float*)HB;                     // 32 MB, 4 g-planes, reuses dead C3
  float*    D2T = (float*)(HB + 33554432);        // 134 MB f32 NHWC, overwrites dead H2/D0

  prep_k<<<1, 256, 0, stream>>>((const unsigned*)x, MODE,
                                w1, b1, w2, b2, w3, b3, wpre, bpre, cbk, wpost, bpost,
                                wd1, bd1, wd2, bd2, wd3, bd3,
                                g1, be1, g2, be2, g3, be3, g4, be4, g5, be5, PF, PD);

  conv1_t<<<8192, 256, 0, stream>>>(x, PF, H1, P1, MODE);
  bn_reduce_k<<<16, 256, 0, stream>>>(P1, 8192, STD + 0, STF + 0, PF + 9856, 1.0 / 2097152.0);

  conv2_t<<<2048, 256, 0, stream>>>(H1, PF, STF + 0, H2, P2);
  bn_reduce_k<<<16, 256, 0, stream>>>(P2, 2048, STD + 32, STF + 32, PF + 9888, 1.0 / 524288.0);

  conv3_k<<<512, 256, 0, stream>>>(H2, PD, STF + 32, C3, P3);
  bn_reduce_k<<<4, 256, 0, stream>>>(P3, 512, STD + 64, STF + 64, PF + 9920, 1.0 / 131072.0);

  vq_k<<<512, 256, 0, stream>>>(C3, PD, STD + 64, D0, VP);

  deconv1_k<<<dim3(512, 4), 256, 0, stream>>>(D0, PF, D1, P4);
  bn_reduce_k<<<16, 256, 0, stream>>>(P4, 2048, STD + 96, STF + 96, PF + 9952, 1.0 / 524288.0);

  deconv2_t<<<2048, 256, 0, stream>>>(D1, PF, STF + 96, D2T, P5);
  bn_reduce_k<<<16, 256, 0, stream>>>(P5, 2048, STD + 128, STF + 128, PF + 9984, 1.0 / 2097152.0);

  deconv3_t<<<8192, 256, 0, stream>>>(D2T, PF, STF + 128, x, d_out, RP, MODE);
  finalize_k<<<1, 256, 0, stream>>>(VP, RP, d_out, MODE);
}